// Round 17
// baseline (1516.238 us; speedup 1.0000x reference)
//
#include <hip/hip_runtime.h>
#include <hip/hip_bf16.h>
#include <math.h>

// SAM vision layer: LN1 -> windowed attention (decomposed rel-pos bias) -> proj
// + residual -> LN2 -> MLP(GELU exact) -> residual.
// B=8, H=W=64, HS=768, NH=12, HD=64, WS=14 -> 200 windows x 196 tokens.

#define HS 768
#define NHEADS 12
#define HD 64
#define WSZ 14
#define TOK 196
#define HWDIM 64
#define NSIDE 5
#define WIN_PER_B 25

typedef __attribute__((ext_vector_type(8))) short short8;
typedef __attribute__((ext_vector_type(4))) float floatx4;
typedef __attribute__((ext_vector_type(4))) unsigned short ushort4v;

__device__ __forceinline__ float bf2f(unsigned short u) {
    union { unsigned int i; float f; } w; w.i = ((unsigned int)u) << 16; return w.f;
}
__device__ __forceinline__ unsigned short f2bu(float f) {
    __hip_bfloat16 h = __float2bfloat16(f);
    return *(unsigned short*)&h;
}

// async global->LDS, 16B per lane. LDS dest must be wave-uniform base;
// HW writes lane l at base + l*16. Global src is per-lane.
__device__ __forceinline__ void gload16(const void* g, void* l) {
    __builtin_amdgcn_global_load_lds(
        (const __attribute__((address_space(1))) void*)g,
        (__attribute__((address_space(3))) void*)l, 16, 0, 0);
}

// window gather: map output row m (chunk-local) -> source spatial row, or -1
__device__ __forceinline__ int gather_src(int m, int M, int win_base) {
    if (m >= M) return -1;
    int lwin = m / TOK, tok = m - lwin * TOK;
    int win = win_base + lwin;
    int bb = win / WIN_PER_B, r = win - bb * WIN_PER_B;
    int wi = r / NSIDE, wj = r - wi * NSIDE;
    int ti = tok / WSZ, tj = tok - ti * WSZ;
    int h = wi * WSZ + ti, w = wj * WSZ + tj;
    if (h < HWDIM && w < HWDIM) return (bb * HWDIM + h) * HWDIM + w;
    return -1;
}

// ---- fp32 -> bf16 transposed convert via LDS tile: src[K][N] -> dst[N][K].
__global__ __launch_bounds__(256)
void cvt_t_k(const float* __restrict__ src, __hip_bfloat16* __restrict__ dst,
             int K, int N) {
    __shared__ float t[32][33];
    int n0 = blockIdx.x * 32, k0 = blockIdx.y * 32;
    int tc = threadIdx.x & 31, tr8 = threadIdx.x >> 5;   // tr8: 0..7
    #pragma unroll
    for (int i = 0; i < 4; ++i) {
        int r = tr8 + i * 8;
        t[r][tc] = src[(size_t)(k0 + r) * N + n0 + tc];
    }
    __syncthreads();
    #pragma unroll
    for (int i = 0; i < 4; ++i) {
        int r = tr8 + i * 8;
        dst[(size_t)(n0 + r) * K + k0 + tc] = __float2bfloat16(t[tc][r]);
    }
}

// ---- LayerNorm over HS=768: one WAVE per row, float4 loads, shuffle-only
// reduce (no LDS, no barrier). 256 threads = 4 rows/block; grid = rows/4.
__global__ __launch_bounds__(256)
void ln_k(const float* __restrict__ x, const float* __restrict__ g,
          const float* __restrict__ b, __hip_bfloat16* __restrict__ y) {
    int wave = threadIdx.x >> 6, lane = threadIdx.x & 63;
    int row = blockIdx.x * 4 + wave;
    const float4* xr = (const float4*)(x + (size_t)row * HS);
    float4 a0 = xr[lane], a1 = xr[lane + 64], a2 = xr[lane + 128];
    float s = a0.x + a0.y + a0.z + a0.w + a1.x + a1.y + a1.z + a1.w
            + a2.x + a2.y + a2.z + a2.w;
    float q = a0.x*a0.x + a0.y*a0.y + a0.z*a0.z + a0.w*a0.w
            + a1.x*a1.x + a1.y*a1.y + a1.z*a1.z + a1.w*a1.w
            + a2.x*a2.x + a2.y*a2.y + a2.z*a2.z + a2.w*a2.w;
    #pragma unroll
    for (int off = 32; off > 0; off >>= 1) {
        s += __shfl_down(s, off, 64);
        q += __shfl_down(q, off, 64);
    }
    s = __shfl(s, 0, 64);
    q = __shfl(q, 0, 64);
    float mu = s * (1.0f / HS);
    float var = q * (1.0f / HS) - mu * mu;
    float rstd = rsqrtf(var + 1e-6f);
    const float4* g4 = (const float4*)g;
    const float4* b4 = (const float4*)b;
    unsigned short* yr = (unsigned short*)y + (size_t)row * HS;
    float4 av[3] = {a0, a1, a2};
    #pragma unroll
    for (int c = 0; c < 3; ++c) {
        float4 gv = g4[lane + 64 * c], bv = b4[lane + 64 * c];
        float4 a = av[c];
        ushort4v o;
        o[0] = f2bu((a.x - mu) * rstd * gv.x + bv.x);
        o[1] = f2bu((a.y - mu) * rstd * gv.y + bv.y);
        o[2] = f2bu((a.z - mu) * rstd * gv.z + bv.z);
        o[3] = f2bu((a.w - mu) * rstd * gv.w + bv.w);
        *(ushort4v*)&yr[(lane + 64 * c) * 4] = o;
    }
}

// ---- bf16 MFMA GEMM, BM x BN tile, BK=32, 4 waves (2x2), wave tile
// (BM/2)x(BN/2). DEPTH-4 LDS ring with counted vmcnt (tiles t+1,t+2 stay in
// flight across the barrier). Both-sides granule XOR swizzle (0 bank
// conflicts, r5). Transposed grid (blockIdx.x = col panel) keeps the A
// row-panel L2-hot. EP0/EP2 epilogues stage the C-tile in LDS and write
// 128B-contiguous segments. Gather-invalid A rows clamp to row 0 (uniform
// vmcnt); garbage discarded at C-stage time.
template<int EP, int AGATHER, int BM, int BN, int KSPLIT>
__global__ __launch_bounds__(256, 4)
void gemm_k(const __hip_bfloat16* __restrict__ A,
            const __hip_bfloat16* __restrict__ Bt,
            const float* __restrict__ bias,
            int M, int N, int K,
            __hip_bfloat16* __restrict__ oq, __hip_bfloat16* __restrict__ okk,
            __hip_bfloat16* __restrict__ ov,
            float* __restrict__ of, const float* __restrict__ resid,
            __hip_bfloat16* __restrict__ oh,
            int win_base, int m_base)
{
    constexpr int LPW = (BM + BN) / 64;     // DMA issues per wave per K-step
    constexpr int FI = BM / 32;
    constexpr int FJ = BN / 32;
    constexpr int ASZ = BM * 32;            // shorts per A buffer
    constexpr int BSZ = BN * 32;
    __shared__ __align__(16) unsigned short lds[4 * (ASZ + BSZ)];
    unsigned short* Asb = lds;
    unsigned short* Bsb = lds + 4 * ASZ;

    int tid = threadIdx.x;
    int wave = tid >> 6, lane = tid & 63;
    int n16 = lane & 15, quad = lane >> 4;
    int wrr = wave >> 1, wcc = wave & 1;
    int bm = blockIdx.y * BM;          // transposed grid
    int bn = blockIdx.x * BN;
    int kz = (KSPLIT > 1) ? blockIdx.z : 0;
    int kseg = K / KSPLIT;

    int srow = tid >> 2;
    int q4 = tid & 3;
    int skoff = (q4 ^ ((srow >> 1) & 3)) << 3;   // swizzled source granule

    const unsigned short* Au = (const unsigned short*)A;
    const unsigned short* Bu = (const unsigned short*)Bt;

    int src0 = 0, src1 = 0;
    if (AGATHER) {
        int s0 = gather_src(bm + srow, M, win_base);
        src0 = s0 >= 0 ? s0 : 0;
        if (BM == 128) {
            int s1 = gather_src(bm + 64 + srow, M, win_base);
            src1 = s1 >= 0 ? s1 : 0;
        }
    } else {
        int m0 = bm + srow;
        src0 = m0 < M ? m0 : 0;
        if (BM == 128) { int m1 = bm + 64 + srow; src1 = m1 < M ? m1 : 0; }
    }

    const unsigned short* ap0 = Au + (size_t)src0 * K + kz * kseg + skoff;
    const unsigned short* ap1 = Au + (size_t)src1 * K + kz * kseg + skoff;
    const unsigned short* bp0 = Bu + (size_t)(bn + srow) * K + kz * kseg + skoff;
    const unsigned short* bp1 = Bu + (size_t)(bn + 64 + srow) * K + kz * kseg + skoff;

    auto stage = [&](int kt, int b) {
        size_t ko = (size_t)kt * 32;
        gload16(ap0 + ko, Asb + b * ASZ + wave * 512);
        if constexpr (BM == 128) gload16(ap1 + ko, Asb + b * ASZ + 2048 + wave * 512);
        gload16(bp0 + ko, Bsb + b * BSZ + wave * 512);
        if constexpr (BN == 128) gload16(bp1 + ko, Bsb + b * BSZ + 2048 + wave * 512);
    };

    floatx4 acc[FI][FJ] = {};
    int xr = (n16 >> 1) & 3;
    int nt = kseg >> 5;

    // prologue: 3 tiles in flight
    stage(0, 0);
    if (nt > 1) stage(1, 1);
    if (nt > 2) stage(2, 2);

    for (int t = 0; t < nt; ++t) {
        int cur = t & 3;
        int ahead = nt - 1 - t;
        if (ahead >= 2) {
            if constexpr (LPW == 4)      asm volatile("s_waitcnt vmcnt(8)" ::: "memory");
            else if constexpr (LPW == 3) asm volatile("s_waitcnt vmcnt(6)" ::: "memory");
            else                         asm volatile("s_waitcnt vmcnt(4)" ::: "memory");
        } else if (ahead == 1) {
            if constexpr (LPW == 4)      asm volatile("s_waitcnt vmcnt(4)" ::: "memory");
            else if constexpr (LPW == 3) asm volatile("s_waitcnt vmcnt(3)" ::: "memory");
            else                         asm volatile("s_waitcnt vmcnt(2)" ::: "memory");
        } else {
            asm volatile("s_waitcnt vmcnt(0)" ::: "memory");
        }
        __builtin_amdgcn_s_barrier();          // tile t visible to all waves
        if (t + 3 < nt) stage(t + 3, (t + 3) & 3);
        short8 af[FI], bf[FJ];
        #pragma unroll
        for (int i = 0; i < FI; ++i) {
            int ra = wrr * (BM / 2) + i * 16 + n16;
            af[i] = *(const short8*)&Asb[cur * ASZ + ra * 32 + ((quad ^ xr) << 3)];
        }
        #pragma unroll
        for (int j = 0; j < FJ; ++j) {
            int rb = wcc * (BN / 2) + j * 16 + n16;
            bf[j] = *(const short8*)&Bsb[cur * BSZ + rb * 32 + ((quad ^ xr) << 3)];
        }
        #pragma unroll
        for (int i = 0; i < FI; ++i)
            #pragma unroll
            for (int j = 0; j < FJ; ++j)
                acc[i][j] = __builtin_amdgcn_mfma_f32_16x16x32_bf16(
                    af[i], bf[j], acc[i][j], 0, 0, 0);
        asm volatile("s_waitcnt lgkmcnt(0)" ::: "memory");  // reads retired
    }

    int rbase = bm + wrr * (BM / 2) + quad * 4;
    int cbase = bn + wcc * (BN / 2) + n16;

    if constexpr (EP == 0 || EP == 2) {
        // ---- C-tile through LDS: coalesced 128B row-half stores ----
        constexpr int CLD = BN + 8;            // padded bf16 row stride
        __syncthreads();                       // staging ring no longer needed
        unsigned short* Cs = lds;
        int ruseW[FI * 4];
        if (EP == 0) {
            #pragma unroll
            for (int i = 0; i < FI; ++i)
                #pragma unroll
                for (int r = 0; r < 4; ++r)
                    ruseW[i * 4 + r] = gather_src(rbase + i * 16 + r, M, win_base) >= 0;
        }
        #pragma unroll
        for (int j = 0; j < FJ; ++j) {
            int col_l = wcc * (BN / 2) + j * 16 + n16;
            float bcol = bias[bn + col_l];
            #pragma unroll
            for (int i = 0; i < FI; ++i) {
                #pragma unroll
                for (int r = 0; r < 4; ++r) {
                    int row_l = wrr * (BM / 2) + i * 16 + quad * 4 + r;
                    float val = acc[i][j][r] + bcol;
                    float vv;
                    if (EP == 0) {
                        vv = ruseW[i * 4 + r] ? val : bcol;
                    } else {
                        vv = 0.5f * val * (1.0f + erff(val * 0.70710678118654752f));
                    }
                    Cs[row_l * CLD + col_l] = f2bu(vv);
                }
            }
        }
        __syncthreads();
        #pragma unroll
        for (int rep = 0; rep < (BM * (BN / 64)) / 256; ++rep) {
            int idx = rep * 256 + tid;
            int row_l = idx / (BN / 64);
            int half = idx - row_l * (BN / 64);
            int m = bm + row_l;
            if (m < M) {
                unsigned short* srcu = &Cs[row_l * CLD + half * 64];
                unsigned short* dstu;
                if (EP == 0) {
                    int lwin = m / TOK, tok = m - lwin * TOK;
                    int colg = bn + half * 64;
                    int which = colg / HS;
                    int head = (colg - which * HS) >> 6;
                    __hip_bfloat16* dstp = (which == 0) ? oq : ((which == 1) ? okk : ov);
                    dstu = (unsigned short*)dstp +
                           ((size_t)(lwin * NHEADS + head) * TOK + tok) * HD;
                } else {
                    dstu = (unsigned short*)oh + (size_t)m * N + bn + half * 64;
                }
                #pragma unroll
                for (int s = 0; s < 8; ++s)
                    *(uint4*)(dstu + s * 8) = *(const uint4*)(srcu + s * 8);
            }
        }
    } else {
        // ---- direct epilogues (EP1 proj fp32 +resid, EP3 accumulate) ----
        int rowoff[FI * 4];
        int ruse[FI * 4];
        #pragma unroll
        for (int i = 0; i < FI; ++i) {
            #pragma unroll
            for (int r = 0; r < 4; ++r) {
                int ii = i * 4 + r;
                int row = rbase + i * 16 + r;
                if (EP == 1) {
                    int lwin = row / TOK, tok = row - lwin * TOK;
                    int win = win_base + lwin;
                    int bb = win / WIN_PER_B, rr2 = win - bb * WIN_PER_B;
                    int wi = rr2 / NSIDE, wj = rr2 - wi * NSIDE;
                    int ti = tok / WSZ, tj = tok - ti * WSZ;
                    int h = wi * WSZ + ti, w = wj * WSZ + tj;
                    ruse[ii] = (h < HWDIM) && (w < HWDIM);
                    rowoff[ii] = ((bb * HWDIM + h) * HWDIM + w) * HS;
                } else {
                    rowoff[ii] = (m_base + row) * HS;
                    ruse[ii] = 1;
                }
            }
        }
        #pragma unroll
        for (int j = 0; j < FJ; ++j) {
            int col = cbase + j * 16;
            float bcol = bias[col];
            if (EP == 3 && KSPLIT > 1 && kz != 0) bcol = 0.0f;
            #pragma unroll
            for (int i = 0; i < FI; ++i) {
                #pragma unroll
                for (int r = 0; r < 4; ++r) {
                    int ii = i * 4 + r;
                    int row = rbase + i * 16 + r;
                    if (row >= M) continue;
                    float val = acc[i][j][r] + bcol;
                    if (EP == 1) {
                        if (ruse[ii]) {
                            size_t idx = (size_t)rowoff[ii] + col;
                            of[idx] = resid[idx] + val;
                        }
                    } else {
                        size_t idx = (size_t)rowoff[ii] + col;
                        if (KSPLIT > 1) {
                            unsafeAtomicAdd(&of[idx], val);
                        } else {
                            of[idx] += val;
                        }
                    }
                }
            }
        }
    }
}

// ---- MFMA attention. One block per (local window, head); 4 waves.
// Ks LDS-staged (stride 72 = 2-way/free); Vt stride 232 (2-way/free).
// V staged via coalesced uint4 row loads + scalar LDS transpose writes;
// s_setprio(1) around the S and PV MFMA clusters. Ks reads for pad rows
// 196..207 overflow into the Vt region: finite bf16 garbage, masked in S.
__global__ __launch_bounds__(256)
void attn_k(const __hip_bfloat16* __restrict__ qb, const __hip_bfloat16* __restrict__ kb,
            const __hip_bfloat16* __restrict__ vb,
            const float* __restrict__ rph, const float* __restrict__ rpw,
            __hip_bfloat16* __restrict__ ao)
{
    __shared__ __align__(16) unsigned short lds[32416];
    unsigned short* Ks = lds;            // [196][72] bf16
    unsigned short* Vt = lds + 14112;    // [64][232] bf16 (cols 196..231 zero)
    unsigned short* scr = lds + 28960;   // 4 x 864

    int bid = blockIdx.x;
    int lwin = bid / NHEADS, head = bid - lwin * NHEADS;
    size_t base = (size_t)(lwin * NHEADS + head) * TOK * HD;
    const unsigned short* q = (const unsigned short*)qb + base;
    const unsigned short* k = (const unsigned short*)kb + base;
    const unsigned short* v = (const unsigned short*)vb + base;

    int tid = threadIdx.x;
    int wave = tid >> 6, lane = tid & 63;
    int n16 = lane & 15, quad = lane >> 4;

    short8 btab[4][2];
    #pragma unroll
    for (int nt = 0; nt < 4; ++nt) {
        int n = nt * 16 + n16;
        #pragma unroll
        for (int kh = 0; kh < 2; ++kh) {
            short8 f = {0, 0, 0, 0, 0, 0, 0, 0};
            if (n < 54) {
                const float* src = (n < 27) ? (rph + (size_t)n * HD)
                                            : (rpw + (size_t)(n - 27) * HD);
                const float4* s4 = (const float4*)(src + kh * 32 + quad * 8);
                float4 a = s4[0], b = s4[1];
                f[0] = (short)f2bu(a.x); f[1] = (short)f2bu(a.y);
                f[2] = (short)f2bu(a.z); f[3] = (short)f2bu(a.w);
                f[4] = (short)f2bu(b.x); f[5] = (short)f2bu(b.y);
                f[6] = (short)f2bu(b.z); f[7] = (short)f2bu(b.w);
            }
            btab[nt][kh] = f;
        }
    }

    // ---- stage K: 196 rows x 64 bf16 (stride 72), coalesced uint4 ----
    for (int idx = tid; idx < 1568; idx += 256) {
        int row = idx >> 3, q8 = (idx & 7) << 3;
        *(uint4*)&Ks[row * 72 + q8] = *(const uint4*)(k + (size_t)row * HD + q8);
    }
    // ---- stage V transposed: coalesced uint4 row loads, scalar LDS writes ----
    for (int s = tid; s < 1568; s += 256) {
        int row = s >> 3, d8 = (s & 7) << 3;
        uint4 vv = *(const uint4*)(v + (size_t)row * HD + d8);
        const unsigned short* p = (const unsigned short*)&vv;
        #pragma unroll
        for (int e = 0; e < 8; ++e)
            Vt[(d8 + e) * 232 + row] = p[e];
    }
    for (int s = tid; s < 64 * 9; s += 256) {    // zero cols 196..231
        int r = s / 9, c = 196 + (s - r * 9) * 4;
        uint2 z = {0u, 0u};
        *(uint2*)&Vt[r * 232 + c] = z;
    }
    __syncthreads();

    unsigned short* myscr = &scr[wave * 864];
    int rl0 = quad * 4;

    for (int qt = wave; qt < 13; qt += 4) {
        int qrow = qt * 16 + n16;
        int qr = qrow < 196 ? qrow : 195;

        short8 qf0 = *(const short8*)(q + (size_t)qr * HD + quad * 8);
        short8 qf1 = *(const short8*)(q + (size_t)qr * HD + 32 + quad * 8);

        // rel bias via MFMA: rel[16 rows][54 cols] -> scr
        #pragma unroll
        for (int nt = 0; nt < 4; ++nt) {
            floatx4 cr = {0.f, 0.f, 0.f, 0.f};
            cr = __builtin_amdgcn_mfma_f32_16x16x32_bf16(qf0, btab[nt][0], cr, 0, 0, 0);
            cr = __builtin_amdgcn_mfma_f32_16x16x32_bf16(qf1, btab[nt][1], cr, 0, 0, 0);
            int c = nt * 16 + n16;
            if (c < 54) {
                #pragma unroll
                for (int r = 0; r < 4; ++r)
                    myscr[(rl0 + r) * 54 + c] = f2bu(cr[r]);
            }
        }

        // S = Q K^T (13 n-tiles, K from LDS)
        floatx4 S[13];
        __builtin_amdgcn_s_setprio(1);
        #pragma unroll
        for (int nt = 0; nt < 13; ++nt) {
            short8 kf0 = *(const short8*)&Ks[(nt * 16 + n16) * 72 + quad * 8];
            short8 kf1 = *(const short8*)&Ks[(nt * 16 + n16) * 72 + 32 + quad * 8];
            floatx4 a = {0.f, 0.f, 0.f, 0.f};
            a = __builtin_amdgcn_mfma_f32_16x16x32_bf16(qf0, kf0, a, 0, 0, 0);
            a = __builtin_amdgcn_mfma_f32_16x16x32_bf16(qf1, kf1, a, 0, 0, 0);
            S[nt] = a;
        }
        __builtin_amdgcn_s_setprio(0);

        int ti4[4], tj4[4];
        #pragma unroll
        for (int r = 0; r < 4; ++r) {
            int grow = qt * 16 + rl0 + r;
            ti4[r] = grow / WSZ;
            tj4[r] = grow - ti4[r] * WSZ;
        }

        #pragma unroll
        for (int nt = 0; nt < 13; ++nt) {
            int col = nt * 16 + n16;
            int ki = col / WSZ, kj = col - ki * WSZ;
            #pragma unroll
            for (int r = 0; r < 4; ++r) {
                float rh = bf2f(myscr[(rl0 + r) * 54 + (ti4[r] - ki + 13)]);
                float rw = bf2f(myscr[(rl0 + r) * 54 + (40 + tj4[r] - kj)]);
                S[nt][r] = fmaf(S[nt][r], 0.125f, rh + rw);
            }
        }
        if (n16 >= 4) {
            #pragma unroll
            for (int r = 0; r < 4; ++r) S[12][r] = -1e30f;
        }

        float mxr[4] = {-3e30f, -3e30f, -3e30f, -3e30f};
        #pragma unroll
        for (int nt = 0; nt < 13; ++nt)
            #pragma unroll
            for (int r = 0; r < 4; ++r) mxr[r] = fmaxf(mxr[r], S[nt][r]);
        #pragma unroll
        for (int m = 1; m <= 8; m <<= 1)
            #pragma unroll
            for (int r = 0; r < 4; ++r) mxr[r] = fmaxf(mxr[r], __shfl_xor(mxr[r], m, 64));
        float sum[4] = {0.f, 0.f, 0.f, 0.f};
        #pragma unroll
        for (int nt = 0; nt < 13; ++nt)
            #pragma unroll
            for (int r = 0; r < 4; ++r) {
                float e = __expf(S[nt][r] - mxr[r]);
                S[nt][r] = e;
                sum[r] += e;
            }
        #pragma unroll
        for (int m = 1; m <= 8; m <<= 1)
            #pragma unroll
            for (int r = 0; r < 4; ++r) sum[r] += __shfl_xor(sum[r], m, 64);
        float inv[4];
        #pragma unroll
        for (int r = 0; r < 4; ++r) inv[r] = 1.0f / sum[r];

        floatx4 O[4] = {{0.f,0.f,0.f,0.f},{0.f,0.f,0.f,0.f},{0.f,0.f,0.f,0.f},{0.f,0.f,0.f,0.f}};
        __builtin_amdgcn_s_setprio(1);
        #pragma unroll
        for (int ks = 0; ks < 7; ++ks) {
            #pragma unroll
            for (int r = 0; r < 4; ++r) {
                myscr[(rl0 + r) * 40 + n16] = f2bu(S[2 * ks][r] * inv[r]);
                myscr[(rl0 + r) * 40 + 16 + n16] =
                    (2 * ks + 1 < 13) ? f2bu(S[2 * ks + 1][r] * inv[r]) : (unsigned short)0;
            }
            short8 pf = *(const short8*)&myscr[n16 * 40 + quad * 8];
            #pragma unroll
            for (int nt4 = 0; nt4 < 4; ++nt4) {
                short8 vf = *(const short8*)&Vt[(nt4 * 16 + n16) * 232 + ks * 32 + quad * 8];
                O[nt4] = __builtin_amdgcn_mfma_f32_16x16x32_bf16(pf, vf, O[nt4], 0, 0, 0);
            }
        }
        __builtin_amdgcn_s_setprio(0);

        #pragma unroll
        for (int nt4 = 0; nt4 < 4; ++nt4) {
            int d = nt4 * 16 + n16;
            #pragma unroll
            for (int r = 0; r < 4; ++r) {
                int row = qt * 16 + rl0 + r;
                if (row < 196) {
                    ao[((size_t)(lwin * TOK + row)) * HS + head * HD + d] =
                        __float2bfloat16(O[nt4][r]);
                }
            }
        }
    }
}

extern "C" void kernel_launch(void* const* d_in, const int* in_sizes, int n_in,
                              void* d_out, int out_size, void* d_ws, size_t ws_size,
                              hipStream_t stream)
{
    const float* x      = (const float*)d_in[0];
    const float* ln1_g  = (const float*)d_in[1];
    const float* ln1_b  = (const float*)d_in[2];
    const float* qkv_w  = (const float*)d_in[3];
    const float* qkv_b  = (const float*)d_in[4];
    const float* proj_w = (const float*)d_in[5];
    const float* proj_b = (const float*)d_in[6];
    const float* rph    = (const float*)d_in[7];
    const float* rpw    = (const float*)d_in[8];
    const float* ln2_g  = (const float*)d_in[9];
    const float* ln2_b  = (const float*)d_in[10];
    const float* mlp_w1 = (const float*)d_in[11];
    const float* mlp_b1 = (const float*)d_in[12];
    const float* mlp_w2 = (const float*)d_in[13];
    const float* mlp_b2 = (const float*)d_in[14];
    float* out = (float*)d_out;

    char* ws = (char*)d_ws;
    __hip_bfloat16* wqkv  = (__hip_bfloat16*)(ws + 0);          // [2304][768]
    __hip_bfloat16* wproj = (__hip_bfloat16*)(ws + 3538944);    // [768][768]
    __hip_bfloat16* wm1   = (__hip_bfloat16*)(ws + 4718592);    // [3072][768]
    __hip_bfloat16* wm2   = (__hip_bfloat16*)(ws + 9437184);    // [768][3072]
    __hip_bfloat16* ybuf  = (__hip_bfloat16*)(ws + 14155776);   // 32768x768
    char* R2 = ws + 64487424;
    __hip_bfloat16* hid = (__hip_bfloat16*)(R2);

    // ---- runtime-tiered attention chunking by workspace size ----
    // per-window q/k/v/ao footprint: 12*196*64*2 = 301056 B per buffer
    const size_t PERWIN = 301056;
    int nwin_chunk, nchunks;
    if (ws_size >= 64487424ull + 4ull * 200 * PERWIN) {         // ~292 MB
        nwin_chunk = 200; nchunks = 1;
    } else if (ws_size >= 64487424ull + 4ull * 100 * PERWIN) {  // ~177 MB
        nwin_chunk = 100; nchunks = 2;
    } else {
        nwin_chunk = 25; nchunks = 8;
    }
    size_t bufsz = (size_t)nwin_chunk * PERWIN;
    __hip_bfloat16* qc = (__hip_bfloat16*)(R2);
    __hip_bfloat16* kc = (__hip_bfloat16*)(R2 + bufsz);
    __hip_bfloat16* vc = (__hip_bfloat16*)(R2 + 2 * bufsz);
    __hip_bfloat16* ao = (__hip_bfloat16*)(R2 + 3 * bufsz);

    // MLP chunking: 2 chunks of 16384 -> hid slice 100 MB (L3-resident
    // between producing MLP1 and consuming MLP2) AND full-round grids
    // (3072/1536 blocks). r14 merged (201 MB hid) = 3x HBM over-fetch on
    // MLP2; r15 4-chunk (768-block MLP2 grids) = tail waste. Middle wins.
    int mlpch, nmlp;
    if (ws_size >= 64487424ull + (size_t)16384 * 3072 * 2) {
        mlpch = 16384; nmlp = 2;
    } else {
        mlpch = 8192; nmlp = 4;
    }

    cvt_t_k<<<dim3(72, 24), 256, 0, stream>>>(qkv_w,  wqkv,  768, 2304);
    cvt_t_k<<<dim3(24, 24), 256, 0, stream>>>(proj_w, wproj, 768, 768);
    cvt_t_k<<<dim3(96, 24), 256, 0, stream>>>(mlp_w1, wm1,   768, 3072);
    cvt_t_k<<<dim3(24, 96), 256, 0, stream>>>(mlp_w2, wm2,  3072, 768);

    ln_k<<<dim3(8192), 256, 0, stream>>>(x, ln1_g, ln1_b, ybuf);

    for (int c = 0; c < nchunks; ++c) {
        int M = nwin_chunk * TOK;
        int wb = c * nwin_chunk;
        gemm_k<0, 1, 128, 128, 1><<<dim3(18, (M + 127) / 128), 256, 0, stream>>>(
            ybuf, wqkv, qkv_b, M, 2304, 768,
            qc, kc, vc, nullptr, nullptr, nullptr, wb, 0);
        attn_k<<<dim3(nwin_chunk * NHEADS), 256, 0, stream>>>(
            qc, kc, vc, rph, rpw, ao);
        gemm_k<1, 0, 128, 128, 1><<<dim3(6, (M + 127) / 128), 256, 0, stream>>>(
            ao, wproj, proj_b, M, 768, 768,
            nullptr, nullptr, nullptr, out, x, nullptr, wb, 0);
    }

    ln_k<<<dim3(8192), 256, 0, stream>>>(out, ln2_g, ln2_b, ybuf);

    for (int mc = 0; mc < nmlp; ++mc) {
        gemm_k<2, 0, 128, 128, 1><<<dim3(24, mlpch / 128), 256, 0, stream>>>(
            ybuf + (size_t)mc * mlpch * HS, wm1, mlp_b1, mlpch, 3072, 768,
            nullptr, nullptr, nullptr, nullptr, nullptr, hid, 0, 0);
        gemm_k<3, 0, 128, 64, 1><<<dim3(12, mlpch / 128), 256, 0, stream>>>(
            hid, wm2, mlp_b2, mlpch, 768, 3072,
            nullptr, nullptr, nullptr, out, nullptr, nullptr, 0, mc * mlpch);
    }
}

// Round 18
// 1415.057 us; speedup vs baseline: 1.0715x; 1.0715x over previous
//
#include <hip/hip_runtime.h>
#include <hip/hip_bf16.h>
#include <math.h>

// SAM vision layer: LN1 -> windowed attention (decomposed rel-pos bias) -> proj
// + residual -> LN2 -> MLP(GELU exact) -> residual.
// B=8, H=W=64, HS=768, NH=12, HD=64, WS=14 -> 200 windows x 196 tokens.

#define HS 768
#define NHEADS 12
#define HD 64
#define WSZ 14
#define TOK 196
#define HWDIM 64
#define NSIDE 5
#define WIN_PER_B 25

typedef __attribute__((ext_vector_type(8))) short short8;
typedef __attribute__((ext_vector_type(4))) float floatx4;
typedef __attribute__((ext_vector_type(4))) unsigned short ushort4v;

__device__ __forceinline__ float bf2f(unsigned short u) {
    union { unsigned int i; float f; } w; w.i = ((unsigned int)u) << 16; return w.f;
}
__device__ __forceinline__ unsigned short f2bu(float f) {
    __hip_bfloat16 h = __float2bfloat16(f);
    return *(unsigned short*)&h;
}

// async global->LDS, 16B per lane. LDS dest must be wave-uniform base;
// HW writes lane l at base + l*16. Global src is per-lane.
__device__ __forceinline__ void gload16(const void* g, void* l) {
    __builtin_amdgcn_global_load_lds(
        (const __attribute__((address_space(1))) void*)g,
        (__attribute__((address_space(3))) void*)l, 16, 0, 0);
}

// window gather: map output row m (chunk-local) -> source spatial row, or -1
__device__ __forceinline__ int gather_src(int m, int M, int win_base) {
    if (m >= M) return -1;
    int lwin = m / TOK, tok = m - lwin * TOK;
    int win = win_base + lwin;
    int bb = win / WIN_PER_B, r = win - bb * WIN_PER_B;
    int wi = r / NSIDE, wj = r - wi * NSIDE;
    int ti = tok / WSZ, tj = tok - ti * WSZ;
    int h = wi * WSZ + ti, w = wj * WSZ + tj;
    if (h < HWDIM && w < HWDIM) return (bb * HWDIM + h) * HWDIM + w;
    return -1;
}

// ---- fp32 -> bf16 transposed convert via LDS tile: src[K][N] -> dst[N][K].
__global__ __launch_bounds__(256)
void cvt_t_k(const float* __restrict__ src, __hip_bfloat16* __restrict__ dst,
             int K, int N) {
    __shared__ float t[32][33];
    int n0 = blockIdx.x * 32, k0 = blockIdx.y * 32;
    int tc = threadIdx.x & 31, tr8 = threadIdx.x >> 5;   // tr8: 0..7
    #pragma unroll
    for (int i = 0; i < 4; ++i) {
        int r = tr8 + i * 8;
        t[r][tc] = src[(size_t)(k0 + r) * N + n0 + tc];
    }
    __syncthreads();
    #pragma unroll
    for (int i = 0; i < 4; ++i) {
        int r = tr8 + i * 8;
        dst[(size_t)(n0 + r) * K + k0 + tc] = __float2bfloat16(t[tc][r]);
    }
}

// ---- LayerNorm over HS=768: one WAVE per row, float4 loads, shuffle-only
// reduce (no LDS, no barrier). 256 threads = 4 rows/block; grid = rows/4.
__global__ __launch_bounds__(256)
void ln_k(const float* __restrict__ x, const float* __restrict__ g,
          const float* __restrict__ b, __hip_bfloat16* __restrict__ y) {
    int wave = threadIdx.x >> 6, lane = threadIdx.x & 63;
    int row = blockIdx.x * 4 + wave;
    const float4* xr = (const float4*)(x + (size_t)row * HS);
    float4 a0 = xr[lane], a1 = xr[lane + 64], a2 = xr[lane + 128];
    float s = a0.x + a0.y + a0.z + a0.w + a1.x + a1.y + a1.z + a1.w
            + a2.x + a2.y + a2.z + a2.w;
    float q = a0.x*a0.x + a0.y*a0.y + a0.z*a0.z + a0.w*a0.w
            + a1.x*a1.x + a1.y*a1.y + a1.z*a1.z + a1.w*a1.w
            + a2.x*a2.x + a2.y*a2.y + a2.z*a2.z + a2.w*a2.w;
    #pragma unroll
    for (int off = 32; off > 0; off >>= 1) {
        s += __shfl_down(s, off, 64);
        q += __shfl_down(q, off, 64);
    }
    s = __shfl(s, 0, 64);
    q = __shfl(q, 0, 64);
    float mu = s * (1.0f / HS);
    float var = q * (1.0f / HS) - mu * mu;
    float rstd = rsqrtf(var + 1e-6f);
    const float4* g4 = (const float4*)g;
    const float4* b4 = (const float4*)b;
    unsigned short* yr = (unsigned short*)y + (size_t)row * HS;
    float4 av[3] = {a0, a1, a2};
    #pragma unroll
    for (int c = 0; c < 3; ++c) {
        float4 gv = g4[lane + 64 * c], bv = b4[lane + 64 * c];
        float4 a = av[c];
        ushort4v o;
        o[0] = f2bu((a.x - mu) * rstd * gv.x + bv.x);
        o[1] = f2bu((a.y - mu) * rstd * gv.y + bv.y);
        o[2] = f2bu((a.z - mu) * rstd * gv.z + bv.z);
        o[3] = f2bu((a.w - mu) * rstd * gv.w + bv.w);
        *(ushort4v*)&yr[(lane + 64 * c) * 4] = o;
    }
}

// ---- bf16 MFMA GEMM, BM x BN tile, BK=32, 4 waves (2x2), wave tile
// (BM/2)x(BN/2). DEPTH-4 LDS ring with counted vmcnt (tiles t+1,t+2 stay in
// flight across the barrier). Both-sides granule XOR swizzle (0 bank
// conflicts, r5). Transposed grid (blockIdx.x = col panel) keeps the A
// row-panel L2-hot. EP0/EP2 epilogues stage the C-tile in LDS and write
// 128B-contiguous segments. Gather-invalid A rows clamp to row 0 (uniform
// vmcnt); garbage discarded at C-stage time.
template<int EP, int AGATHER, int BM, int BN, int KSPLIT>
__global__ __launch_bounds__(256, 4)
void gemm_k(const __hip_bfloat16* __restrict__ A,
            const __hip_bfloat16* __restrict__ Bt,
            const float* __restrict__ bias,
            int M, int N, int K,
            __hip_bfloat16* __restrict__ oq, __hip_bfloat16* __restrict__ okk,
            __hip_bfloat16* __restrict__ ov,
            float* __restrict__ of, const float* __restrict__ resid,
            __hip_bfloat16* __restrict__ oh,
            int win_base, int m_base)
{
    constexpr int LPW = (BM + BN) / 64;     // DMA issues per wave per K-step
    constexpr int FI = BM / 32;
    constexpr int FJ = BN / 32;
    constexpr int ASZ = BM * 32;            // shorts per A buffer
    constexpr int BSZ = BN * 32;
    __shared__ __align__(16) unsigned short lds[4 * (ASZ + BSZ)];
    unsigned short* Asb = lds;
    unsigned short* Bsb = lds + 4 * ASZ;

    int tid = threadIdx.x;
    int wave = tid >> 6, lane = tid & 63;
    int n16 = lane & 15, quad = lane >> 4;
    int wrr = wave >> 1, wcc = wave & 1;
    int bm = blockIdx.y * BM;          // transposed grid
    int bn = blockIdx.x * BN;
    int kz = (KSPLIT > 1) ? blockIdx.z : 0;
    int kseg = K / KSPLIT;

    int srow = tid >> 2;
    int q4 = tid & 3;
    int skoff = (q4 ^ ((srow >> 1) & 3)) << 3;   // swizzled source granule

    const unsigned short* Au = (const unsigned short*)A;
    const unsigned short* Bu = (const unsigned short*)Bt;

    int src0 = 0, src1 = 0;
    if (AGATHER) {
        int s0 = gather_src(bm + srow, M, win_base);
        src0 = s0 >= 0 ? s0 : 0;
        if (BM == 128) {
            int s1 = gather_src(bm + 64 + srow, M, win_base);
            src1 = s1 >= 0 ? s1 : 0;
        }
    } else {
        int m0 = bm + srow;
        src0 = m0 < M ? m0 : 0;
        if (BM == 128) { int m1 = bm + 64 + srow; src1 = m1 < M ? m1 : 0; }
    }

    const unsigned short* ap0 = Au + (size_t)src0 * K + kz * kseg + skoff;
    const unsigned short* ap1 = Au + (size_t)src1 * K + kz * kseg + skoff;
    const unsigned short* bp0 = Bu + (size_t)(bn + srow) * K + kz * kseg + skoff;
    const unsigned short* bp1 = Bu + (size_t)(bn + 64 + srow) * K + kz * kseg + skoff;

    auto stage = [&](int kt, int b) {
        size_t ko = (size_t)kt * 32;
        gload16(ap0 + ko, Asb + b * ASZ + wave * 512);
        if constexpr (BM == 128) gload16(ap1 + ko, Asb + b * ASZ + 2048 + wave * 512);
        gload16(bp0 + ko, Bsb + b * BSZ + wave * 512);
        if constexpr (BN == 128) gload16(bp1 + ko, Bsb + b * BSZ + 2048 + wave * 512);
    };

    floatx4 acc[FI][FJ] = {};
    int xr = (n16 >> 1) & 3;
    int nt = kseg >> 5;

    // prologue: 3 tiles in flight
    stage(0, 0);
    if (nt > 1) stage(1, 1);
    if (nt > 2) stage(2, 2);

    for (int t = 0; t < nt; ++t) {
        int cur = t & 3;
        int ahead = nt - 1 - t;
        if (ahead >= 2) {
            if constexpr (LPW == 4)      asm volatile("s_waitcnt vmcnt(8)" ::: "memory");
            else if constexpr (LPW == 3) asm volatile("s_waitcnt vmcnt(6)" ::: "memory");
            else                         asm volatile("s_waitcnt vmcnt(4)" ::: "memory");
        } else if (ahead == 1) {
            if constexpr (LPW == 4)      asm volatile("s_waitcnt vmcnt(4)" ::: "memory");
            else if constexpr (LPW == 3) asm volatile("s_waitcnt vmcnt(3)" ::: "memory");
            else                         asm volatile("s_waitcnt vmcnt(2)" ::: "memory");
        } else {
            asm volatile("s_waitcnt vmcnt(0)" ::: "memory");
        }
        __builtin_amdgcn_s_barrier();          // tile t visible to all waves
        if (t + 3 < nt) stage(t + 3, (t + 3) & 3);
        short8 af[FI], bf[FJ];
        #pragma unroll
        for (int i = 0; i < FI; ++i) {
            int ra = wrr * (BM / 2) + i * 16 + n16;
            af[i] = *(const short8*)&Asb[cur * ASZ + ra * 32 + ((quad ^ xr) << 3)];
        }
        #pragma unroll
        for (int j = 0; j < FJ; ++j) {
            int rb = wcc * (BN / 2) + j * 16 + n16;
            bf[j] = *(const short8*)&Bsb[cur * BSZ + rb * 32 + ((quad ^ xr) << 3)];
        }
        #pragma unroll
        for (int i = 0; i < FI; ++i)
            #pragma unroll
            for (int j = 0; j < FJ; ++j)
                acc[i][j] = __builtin_amdgcn_mfma_f32_16x16x32_bf16(
                    af[i], bf[j], acc[i][j], 0, 0, 0);
        asm volatile("s_waitcnt lgkmcnt(0)" ::: "memory");  // reads retired
    }

    int rbase = bm + wrr * (BM / 2) + quad * 4;
    int cbase = bn + wcc * (BN / 2) + n16;

    if constexpr (EP == 0 || EP == 2) {
        // ---- C-tile through LDS: coalesced 128B row-half stores ----
        constexpr int CLD = BN + 8;            // padded bf16 row stride
        __syncthreads();                       // staging ring no longer needed
        unsigned short* Cs = lds;
        int ruseW[FI * 4];
        if (EP == 0) {
            #pragma unroll
            for (int i = 0; i < FI; ++i)
                #pragma unroll
                for (int r = 0; r < 4; ++r)
                    ruseW[i * 4 + r] = gather_src(rbase + i * 16 + r, M, win_base) >= 0;
        }
        #pragma unroll
        for (int j = 0; j < FJ; ++j) {
            int col_l = wcc * (BN / 2) + j * 16 + n16;
            float bcol = bias[bn + col_l];
            #pragma unroll
            for (int i = 0; i < FI; ++i) {
                #pragma unroll
                for (int r = 0; r < 4; ++r) {
                    int row_l = wrr * (BM / 2) + i * 16 + quad * 4 + r;
                    float val = acc[i][j][r] + bcol;
                    float vv;
                    if (EP == 0) {
                        vv = ruseW[i * 4 + r] ? val : bcol;
                    } else {
                        vv = 0.5f * val * (1.0f + erff(val * 0.70710678118654752f));
                    }
                    Cs[row_l * CLD + col_l] = f2bu(vv);
                }
            }
        }
        __syncthreads();
        #pragma unroll
        for (int rep = 0; rep < (BM * (BN / 64)) / 256; ++rep) {
            int idx = rep * 256 + tid;
            int row_l = idx / (BN / 64);
            int half = idx - row_l * (BN / 64);
            int m = bm + row_l;
            if (m < M) {
                unsigned short* srcu = &Cs[row_l * CLD + half * 64];
                unsigned short* dstu;
                if (EP == 0) {
                    int lwin = m / TOK, tok = m - lwin * TOK;
                    int colg = bn + half * 64;
                    int which = colg / HS;
                    int head = (colg - which * HS) >> 6;
                    __hip_bfloat16* dstp = (which == 0) ? oq : ((which == 1) ? okk : ov);
                    dstu = (unsigned short*)dstp +
                           ((size_t)(lwin * NHEADS + head) * TOK + tok) * HD;
                } else {
                    dstu = (unsigned short*)oh + (size_t)m * N + bn + half * 64;
                }
                #pragma unroll
                for (int s = 0; s < 8; ++s)
                    *(uint4*)(dstu + s * 8) = *(const uint4*)(srcu + s * 8);
            }
        }
    } else {
        // ---- direct epilogues (EP1 proj fp32 +resid, EP3 accumulate) ----
        int rowoff[FI * 4];
        int ruse[FI * 4];
        #pragma unroll
        for (int i = 0; i < FI; ++i) {
            #pragma unroll
            for (int r = 0; r < 4; ++r) {
                int ii = i * 4 + r;
                int row = rbase + i * 16 + r;
                if (EP == 1) {
                    int lwin = row / TOK, tok = row - lwin * TOK;
                    int win = win_base + lwin;
                    int bb = win / WIN_PER_B, rr2 = win - bb * WIN_PER_B;
                    int wi = rr2 / NSIDE, wj = rr2 - wi * NSIDE;
                    int ti = tok / WSZ, tj = tok - ti * WSZ;
                    int h = wi * WSZ + ti, w = wj * WSZ + tj;
                    ruse[ii] = (h < HWDIM) && (w < HWDIM);
                    rowoff[ii] = ((bb * HWDIM + h) * HWDIM + w) * HS;
                } else {
                    rowoff[ii] = (m_base + row) * HS;
                    ruse[ii] = 1;
                }
            }
        }
        #pragma unroll
        for (int j = 0; j < FJ; ++j) {
            int col = cbase + j * 16;
            float bcol = bias[col];
            if (EP == 3 && KSPLIT > 1 && kz != 0) bcol = 0.0f;
            #pragma unroll
            for (int i = 0; i < FI; ++i) {
                #pragma unroll
                for (int r = 0; r < 4; ++r) {
                    int ii = i * 4 + r;
                    int row = rbase + i * 16 + r;
                    if (row >= M) continue;
                    float val = acc[i][j][r] + bcol;
                    if (EP == 1) {
                        if (ruse[ii]) {
                            size_t idx = (size_t)rowoff[ii] + col;
                            of[idx] = resid[idx] + val;
                        }
                    } else {
                        size_t idx = (size_t)rowoff[ii] + col;
                        if (KSPLIT > 1) {
                            unsafeAtomicAdd(&of[idx], val);
                        } else {
                            of[idx] += val;
                        }
                    }
                }
            }
        }
    }
}

// ---- MFMA attention. One block per (local window, head); 4 waves.
// r18: rel-pos bias folded INTO the QK^T MFMA via extended K (one-hot cols):
// S[q][k] = (0.125 q)·k + qe·ke where ke = [one-hot(ki), one-hot(kj), 0..]
// (32 extra dims staged once in KE[208][40]) and qe[64+i] = rel[q][ti+13-i],
// qe[78+j] = relw[q][tj+13-j] (8 scalar LDS reads/lane/q-tile instead of the
// old 104-read bias gather). Scale bookkeeping: q-frags x0.125 (exact pow2),
// rel tables x8 at btab build -> rel stays unscaled, QK gets 1/sqrt(d).
// Ks stride 72, Vt stride 232, KE stride 40 (all 2-way/free). LDS 81472 B
// -> 2 blocks/CU. Ks reads for pad rows 196..207 overflow into Vt: finite
// bf16 garbage; KE pad rows staged zero; masked in S (n16>=4 of nt=12).
__global__ __launch_bounds__(256)
void attn_k(const __hip_bfloat16* __restrict__ qb, const __hip_bfloat16* __restrict__ kb,
            const __hip_bfloat16* __restrict__ vb,
            const float* __restrict__ rph, const float* __restrict__ rpw,
            __hip_bfloat16* __restrict__ ao)
{
    __shared__ __align__(16) unsigned short lds[40736];
    unsigned short* Ks = lds;            // [196][72] bf16
    unsigned short* Vt = lds + 14112;    // [64][232] bf16 (cols 196..231 zero)
    unsigned short* KE = lds + 28960;    // [208][40] bf16 one-hot extension
    unsigned short* scr = lds + 37280;   // 4 x 864

    int bid = blockIdx.x;
    int lwin = bid / NHEADS, head = bid - lwin * NHEADS;
    size_t base = (size_t)(lwin * NHEADS + head) * TOK * HD;
    const unsigned short* q = (const unsigned short*)qb + base;
    const unsigned short* k = (const unsigned short*)kb + base;
    const unsigned short* v = (const unsigned short*)vb + base;

    int tid = threadIdx.x;
    int wave = tid >> 6, lane = tid & 63;
    int n16 = lane & 15, quad = lane >> 4;

    // rel tables x8 (compensates the 0.125-scaled q in the rel MFMA)
    short8 btab[4][2];
    #pragma unroll
    for (int nt = 0; nt < 4; ++nt) {
        int n = nt * 16 + n16;
        #pragma unroll
        for (int kh = 0; kh < 2; ++kh) {
            short8 f = {0, 0, 0, 0, 0, 0, 0, 0};
            if (n < 54) {
                const float* src = (n < 27) ? (rph + (size_t)n * HD)
                                            : (rpw + (size_t)(n - 27) * HD);
                const float4* s4 = (const float4*)(src + kh * 32 + quad * 8);
                float4 a = s4[0], b = s4[1];
                f[0] = (short)f2bu(a.x * 8.0f); f[1] = (short)f2bu(a.y * 8.0f);
                f[2] = (short)f2bu(a.z * 8.0f); f[3] = (short)f2bu(a.w * 8.0f);
                f[4] = (short)f2bu(b.x * 8.0f); f[5] = (short)f2bu(b.y * 8.0f);
                f[6] = (short)f2bu(b.z * 8.0f); f[7] = (short)f2bu(b.w * 8.0f);
            }
            btab[nt][kh] = f;
        }
    }

    // ---- stage K: 196 rows x 64 bf16 (stride 72), coalesced uint4 ----
    for (int idx = tid; idx < 1568; idx += 256) {
        int row = idx >> 3, q8 = (idx & 7) << 3;
        *(uint4*)&Ks[row * 72 + q8] = *(const uint4*)(k + (size_t)row * HD + q8);
    }
    // ---- stage V transposed: coalesced uint4 row loads, scalar LDS writes ----
    for (int s = tid; s < 1568; s += 256) {
        int row = s >> 3, d8 = (s & 7) << 3;
        uint4 vv = *(const uint4*)(v + (size_t)row * HD + d8);
        const unsigned short* p = (const unsigned short*)&vv;
        #pragma unroll
        for (int e = 0; e < 8; ++e)
            Vt[(d8 + e) * 232 + row] = p[e];
    }
    for (int s = tid; s < 64 * 9; s += 256) {    // zero cols 196..231
        int r = s / 9, c = 196 + (s - r * 9) * 4;
        uint2 z = {0u, 0u};
        *(uint2*)&Vt[r * 232 + c] = z;
    }
    // ---- stage KE one-hot: rows 0..195 = [1@ki | 1@14+kj | 0 pad]; 196..207 = 0
    for (int krow = tid; krow < 208; krow += 256) {
        int ki = krow / WSZ, kj = krow - ki * WSZ;
        int valid = krow < TOK;
        #pragma unroll
        for (int c = 0; c < 32; ++c) {
            unsigned short vv = 0;
            if (valid && (c == ki || c == 14 + kj)) vv = 0x3F80;  // bf16 1.0
            KE[krow * 40 + c] = vv;
        }
    }
    __syncthreads();

    unsigned short* myscr = &scr[wave * 864];
    int rl0 = quad * 4;

    for (int qt = wave; qt < 13; qt += 4) {
        int qrow = qt * 16 + n16;
        int qr = qrow < 196 ? qrow : 195;

        // load q frags and scale x0.125 (exact: pow2 exponent shift)
        short8 raw0 = *(const short8*)(q + (size_t)qr * HD + quad * 8);
        short8 raw1 = *(const short8*)(q + (size_t)qr * HD + 32 + quad * 8);
        short8 qf0, qf1;
        #pragma unroll
        for (int e = 0; e < 8; ++e) {
            qf0[e] = (short)f2bu(bf2f((unsigned short)raw0[e]) * 0.125f);
            qf1[e] = (short)f2bu(bf2f((unsigned short)raw1[e]) * 0.125f);
        }

        // rel bias via MFMA: rel[16 rows][54 cols] -> scr (unscaled: q/8 * 8tab)
        #pragma unroll
        for (int nt = 0; nt < 4; ++nt) {
            floatx4 cr = {0.f, 0.f, 0.f, 0.f};
            cr = __builtin_amdgcn_mfma_f32_16x16x32_bf16(qf0, btab[nt][0], cr, 0, 0, 0);
            cr = __builtin_amdgcn_mfma_f32_16x16x32_bf16(qf1, btab[nt][1], cr, 0, 0, 0);
            int c = nt * 16 + n16;
            if (c < 54) {
                #pragma unroll
                for (int r = 0; r < 4; ++r)
                    myscr[(rl0 + r) * 54 + c] = f2bu(cr[r]);
            }
        }

        // build extended-q fragment: qe[64+d] picked from this lane's rel row
        int ti_l = qr / WSZ, tj_l = qr - ti_l * WSZ;
        short8 qf2;
        #pragma unroll
        for (int e = 0; e < 8; ++e) {
            int d = quad * 8 + e;
            int idx_i = n16 * 54 + ti_l + 13 - d;
            int idx_j = n16 * 54 + 40 + tj_l - (d - 14);
            int idx = (d < 14) ? idx_i : idx_j;
            unsigned short vv = (d < 28) ? myscr[idx] : (unsigned short)0;
            qf2[e] = (short)vv;
        }

        // S = 0.125*QK^T + bias (3 k-steps: K 0..63 + one-hot 64..95)
        floatx4 S[13];
        __builtin_amdgcn_s_setprio(1);
        #pragma unroll
        for (int nt = 0; nt < 13; ++nt) {
            int kr = nt * 16 + n16;
            short8 kf0 = *(const short8*)&Ks[kr * 72 + quad * 8];
            short8 kf1 = *(const short8*)&Ks[kr * 72 + 32 + quad * 8];
            short8 kf2 = *(const short8*)&KE[kr * 40 + quad * 8];
            floatx4 a = {0.f, 0.f, 0.f, 0.f};
            a = __builtin_amdgcn_mfma_f32_16x16x32_bf16(qf0, kf0, a, 0, 0, 0);
            a = __builtin_amdgcn_mfma_f32_16x16x32_bf16(qf1, kf1, a, 0, 0, 0);
            a = __builtin_amdgcn_mfma_f32_16x16x32_bf16(qf2, kf2, a, 0, 0, 0);
            S[nt] = a;
        }
        __builtin_amdgcn_s_setprio(0);

        if (n16 >= 4) {
            #pragma unroll
            for (int r = 0; r < 4; ++r) S[12][r] = -1e30f;
        }

        float mxr[4] = {-3e30f, -3e30f, -3e30f, -3e30f};
        #pragma unroll
        for (int nt = 0; nt < 13; ++nt)
            #pragma unroll
            for (int r = 0; r < 4; ++r) mxr[r] = fmaxf(mxr[r], S[nt][r]);
        #pragma unroll
        for (int m = 1; m <= 8; m <<= 1)
            #pragma unroll
            for (int r = 0; r < 4; ++r) mxr[r] = fmaxf(mxr[r], __shfl_xor(mxr[r], m, 64));
        float sum[4] = {0.f, 0.f, 0.f, 0.f};
        #pragma unroll
        for (int nt = 0; nt < 13; ++nt)
            #pragma unroll
            for (int r = 0; r < 4; ++r) {
                float e = __expf(S[nt][r] - mxr[r]);
                S[nt][r] = e;
                sum[r] += e;
            }
        #pragma unroll
        for (int m = 1; m <= 8; m <<= 1)
            #pragma unroll
            for (int r = 0; r < 4; ++r) sum[r] += __shfl_xor(sum[r], m, 64);
        float inv[4];
        #pragma unroll
        for (int r = 0; r < 4; ++r) inv[r] = 1.0f / sum[r];

        floatx4 O[4] = {{0.f,0.f,0.f,0.f},{0.f,0.f,0.f,0.f},{0.f,0.f,0.f,0.f},{0.f,0.f,0.f,0.f}};
        __builtin_amdgcn_s_setprio(1);
        #pragma unroll
        for (int ks = 0; ks < 7; ++ks) {
            #pragma unroll
            for (int r = 0; r < 4; ++r) {
                myscr[(rl0 + r) * 40 + n16] = f2bu(S[2 * ks][r] * inv[r]);
                myscr[(rl0 + r) * 40 + 16 + n16] =
                    (2 * ks + 1 < 13) ? f2bu(S[2 * ks + 1][r] * inv[r]) : (unsigned short)0;
            }
            short8 pf = *(const short8*)&myscr[n16 * 40 + quad * 8];
            #pragma unroll
            for (int nt4 = 0; nt4 < 4; ++nt4) {
                short8 vf = *(const short8*)&Vt[(nt4 * 16 + n16) * 232 + ks * 32 + quad * 8];
                O[nt4] = __builtin_amdgcn_mfma_f32_16x16x32_bf16(pf, vf, O[nt4], 0, 0, 0);
            }
        }
        __builtin_amdgcn_s_setprio(0);

        #pragma unroll
        for (int nt4 = 0; nt4 < 4; ++nt4) {
            int d = nt4 * 16 + n16;
            #pragma unroll
            for (int r = 0; r < 4; ++r) {
                int row = qt * 16 + rl0 + r;
                if (row < 196) {
                    ao[((size_t)(lwin * TOK + row)) * HS + head * HD + d] =
                        __float2bfloat16(O[nt4][r]);
                }
            }
        }
    }
}

extern "C" void kernel_launch(void* const* d_in, const int* in_sizes, int n_in,
                              void* d_out, int out_size, void* d_ws, size_t ws_size,
                              hipStream_t stream)
{
    const float* x      = (const float*)d_in[0];
    const float* ln1_g  = (const float*)d_in[1];
    const float* ln1_b  = (const float*)d_in[2];
    const float* qkv_w  = (const float*)d_in[3];
    const float* qkv_b  = (const float*)d_in[4];
    const float* proj_w = (const float*)d_in[5];
    const float* proj_b = (const float*)d_in[6];
    const float* rph    = (const float*)d_in[7];
    const float* rpw    = (const float*)d_in[8];
    const float* ln2_g  = (const float*)d_in[9];
    const float* ln2_b  = (const float*)d_in[10];
    const float* mlp_w1 = (const float*)d_in[11];
    const float* mlp_b1 = (const float*)d_in[12];
    const float* mlp_w2 = (const float*)d_in[13];
    const float* mlp_b2 = (const float*)d_in[14];
    float* out = (float*)d_out;

    char* ws = (char*)d_ws;
    __hip_bfloat16* wqkv  = (__hip_bfloat16*)(ws + 0);          // [2304][768]
    __hip_bfloat16* wproj = (__hip_bfloat16*)(ws + 3538944);    // [768][768]
    __hip_bfloat16* wm1   = (__hip_bfloat16*)(ws + 4718592);    // [3072][768]
    __hip_bfloat16* wm2   = (__hip_bfloat16*)(ws + 9437184);    // [768][3072]
    __hip_bfloat16* ybuf  = (__hip_bfloat16*)(ws + 14155776);   // 32768x768
    char* R2 = ws + 64487424;
    __hip_bfloat16* hid = (__hip_bfloat16*)(R2);

    // ---- runtime-tiered attention chunking by workspace size ----
    // per-window q/k/v/ao footprint: 12*196*64*2 = 301056 B per buffer
    const size_t PERWIN = 301056;
    int nwin_chunk, nchunks;
    if (ws_size >= 64487424ull + 4ull * 200 * PERWIN) {         // ~292 MB
        nwin_chunk = 200; nchunks = 1;
    } else if (ws_size >= 64487424ull + 4ull * 100 * PERWIN) {  // ~177 MB
        nwin_chunk = 100; nchunks = 2;
    } else {
        nwin_chunk = 25; nchunks = 8;
    }
    size_t bufsz = (size_t)nwin_chunk * PERWIN;
    __hip_bfloat16* qc = (__hip_bfloat16*)(R2);
    __hip_bfloat16* kc = (__hip_bfloat16*)(R2 + bufsz);
    __hip_bfloat16* vc = (__hip_bfloat16*)(R2 + 2 * bufsz);
    __hip_bfloat16* ao = (__hip_bfloat16*)(R2 + 3 * bufsz);

    // MLP chunking: 2 chunks of 16384 (hid slice 100 MB L3-resident,
    // full-round grids); fallback 4 x 8192
    int mlpch, nmlp;
    if (ws_size >= 64487424ull + (size_t)16384 * 3072 * 2) {
        mlpch = 16384; nmlp = 2;
    } else {
        mlpch = 8192; nmlp = 4;
    }

    cvt_t_k<<<dim3(72, 24), 256, 0, stream>>>(qkv_w,  wqkv,  768, 2304);
    cvt_t_k<<<dim3(24, 24), 256, 0, stream>>>(proj_w, wproj, 768, 768);
    cvt_t_k<<<dim3(96, 24), 256, 0, stream>>>(mlp_w1, wm1,   768, 3072);
    cvt_t_k<<<dim3(24, 96), 256, 0, stream>>>(mlp_w2, wm2,  3072, 768);

    ln_k<<<dim3(8192), 256, 0, stream>>>(x, ln1_g, ln1_b, ybuf);

    for (int c = 0; c < nchunks; ++c) {
        int M = nwin_chunk * TOK;
        int wb = c * nwin_chunk;
        gemm_k<0, 1, 128, 128, 1><<<dim3(18, (M + 127) / 128), 256, 0, stream>>>(
            ybuf, wqkv, qkv_b, M, 2304, 768,
            qc, kc, vc, nullptr, nullptr, nullptr, wb, 0);
        attn_k<<<dim3(nwin_chunk * NHEADS), 256, 0, stream>>>(
            qc, kc, vc, rph, rpw, ao);
        gemm_k<1, 0, 128, 128, 1><<<dim3(6, (M + 127) / 128), 256, 0, stream>>>(
            ao, wproj, proj_b, M, 768, 768,
            nullptr, nullptr, nullptr, out, x, nullptr, wb, 0);
    }

    ln_k<<<dim3(8192), 256, 0, stream>>>(out, ln2_g, ln2_b, ybuf);

    for (int mc = 0; mc < nmlp; ++mc) {
        gemm_k<2, 0, 128, 128, 1><<<dim3(24, mlpch / 128), 256, 0, stream>>>(
            ybuf + (size_t)mc * mlpch * HS, wm1, mlp_b1, mlpch, 3072, 768,
            nullptr, nullptr, nullptr, nullptr, nullptr, hid, 0, 0);
        gemm_k<3, 0, 128, 64, 1><<<dim3(12, mlpch / 128), 256, 0, stream>>>(
            hid, wm2, mlp_b2, mlpch, 768, 3072,
            nullptr, nullptr, nullptr, out, nullptr, nullptr, 0, mc * mlpch);
    }
}

// Round 19
// 1404.351 us; speedup vs baseline: 1.0797x; 1.0076x over previous
//
#include <hip/hip_runtime.h>
#include <hip/hip_bf16.h>
#include <math.h>

// SAM vision layer: LN1 -> windowed attention (decomposed rel-pos bias) -> proj
// + residual -> LN2 -> MLP(GELU exact) -> residual.
// B=8, H=W=64, HS=768, NH=12, HD=64, WS=14 -> 200 windows x 196 tokens.

#define HS 768
#define NHEADS 12
#define HD 64
#define WSZ 14
#define TOK 196
#define HWDIM 64
#define NSIDE 5
#define WIN_PER_B 25

typedef __attribute__((ext_vector_type(8))) short short8;
typedef __attribute__((ext_vector_type(4))) float floatx4;
typedef __attribute__((ext_vector_type(4))) unsigned short ushort4v;

__device__ __forceinline__ float bf2f(unsigned short u) {
    union { unsigned int i; float f; } w; w.i = ((unsigned int)u) << 16; return w.f;
}
__device__ __forceinline__ unsigned short f2bu(float f) {
    __hip_bfloat16 h = __float2bfloat16(f);
    return *(unsigned short*)&h;
}

// async global->LDS, 16B per lane. LDS dest must be wave-uniform base;
// HW writes lane l at base + l*16. Global src is per-lane.
__device__ __forceinline__ void gload16(const void* g, void* l) {
    __builtin_amdgcn_global_load_lds(
        (const __attribute__((address_space(1))) void*)g,
        (__attribute__((address_space(3))) void*)l, 16, 0, 0);
}

// window gather: map output row m (chunk-local) -> source spatial row, or -1
__device__ __forceinline__ int gather_src(int m, int M, int win_base) {
    if (m >= M) return -1;
    int lwin = m / TOK, tok = m - lwin * TOK;
    int win = win_base + lwin;
    int bb = win / WIN_PER_B, r = win - bb * WIN_PER_B;
    int wi = r / NSIDE, wj = r - wi * NSIDE;
    int ti = tok / WSZ, tj = tok - ti * WSZ;
    int h = wi * WSZ + ti, w = wj * WSZ + tj;
    if (h < HWDIM && w < HWDIM) return (bb * HWDIM + h) * HWDIM + w;
    return -1;
}

// ---- fp32 -> bf16 transposed convert via LDS tile: src[K][N] -> dst[N][K].
__global__ __launch_bounds__(256)
void cvt_t_k(const float* __restrict__ src, __hip_bfloat16* __restrict__ dst,
             int K, int N) {
    __shared__ float t[32][33];
    int n0 = blockIdx.x * 32, k0 = blockIdx.y * 32;
    int tc = threadIdx.x & 31, tr8 = threadIdx.x >> 5;   // tr8: 0..7
    #pragma unroll
    for (int i = 0; i < 4; ++i) {
        int r = tr8 + i * 8;
        t[r][tc] = src[(size_t)(k0 + r) * N + n0 + tc];
    }
    __syncthreads();
    #pragma unroll
    for (int i = 0; i < 4; ++i) {
        int r = tr8 + i * 8;
        dst[(size_t)(n0 + r) * K + k0 + tc] = __float2bfloat16(t[tc][r]);
    }
}

// ---- LayerNorm over HS=768: one WAVE per row, float4 loads, shuffle-only
// reduce (no LDS, no barrier). 256 threads = 4 rows/block; grid = rows/4.
__global__ __launch_bounds__(256)
void ln_k(const float* __restrict__ x, const float* __restrict__ g,
          const float* __restrict__ b, __hip_bfloat16* __restrict__ y) {
    int wave = threadIdx.x >> 6, lane = threadIdx.x & 63;
    int row = blockIdx.x * 4 + wave;
    const float4* xr = (const float4*)(x + (size_t)row * HS);
    float4 a0 = xr[lane], a1 = xr[lane + 64], a2 = xr[lane + 128];
    float s = a0.x + a0.y + a0.z + a0.w + a1.x + a1.y + a1.z + a1.w
            + a2.x + a2.y + a2.z + a2.w;
    float q = a0.x*a0.x + a0.y*a0.y + a0.z*a0.z + a0.w*a0.w
            + a1.x*a1.x + a1.y*a1.y + a1.z*a1.z + a1.w*a1.w
            + a2.x*a2.x + a2.y*a2.y + a2.z*a2.z + a2.w*a2.w;
    #pragma unroll
    for (int off = 32; off > 0; off >>= 1) {
        s += __shfl_down(s, off, 64);
        q += __shfl_down(q, off, 64);
    }
    s = __shfl(s, 0, 64);
    q = __shfl(q, 0, 64);
    float mu = s * (1.0f / HS);
    float var = q * (1.0f / HS) - mu * mu;
    float rstd = rsqrtf(var + 1e-6f);
    const float4* g4 = (const float4*)g;
    const float4* b4 = (const float4*)b;
    unsigned short* yr = (unsigned short*)y + (size_t)row * HS;
    float4 av[3] = {a0, a1, a2};
    #pragma unroll
    for (int c = 0; c < 3; ++c) {
        float4 gv = g4[lane + 64 * c], bv = b4[lane + 64 * c];
        float4 a = av[c];
        ushort4v o;
        o[0] = f2bu((a.x - mu) * rstd * gv.x + bv.x);
        o[1] = f2bu((a.y - mu) * rstd * gv.y + bv.y);
        o[2] = f2bu((a.z - mu) * rstd * gv.z + bv.z);
        o[3] = f2bu((a.w - mu) * rstd * gv.w + bv.w);
        *(ushort4v*)&yr[(lane + 64 * c) * 4] = o;
    }
}

// ---- bf16 MFMA GEMM, BM x BN tile, BK=32, 4 waves (2x2), wave tile
// (BM/2)x(BN/2). DEPTH-4 LDS ring with counted vmcnt (tiles t+1,t+2 stay in
// flight across the barrier). Both-sides granule XOR swizzle (0 bank
// conflicts, r5). Transposed grid (blockIdx.x = col panel) keeps the A
// row-panel L2-hot. XSWZ=1: bijective XCD swizzle (m204) -- each XCD gets a
// CONTIGUOUS run of x-fastest tile ids, so every A row-panel is fetched by
// exactly ONE XCD's L2 (fixes the 5.3x A over-fetch measured on merged QKV:
// FETCH 267 MB vs 54 logical, r18). EP0/EP2 epilogues stage the C-tile in
// LDS and write 128B-contiguous segments. Gather-invalid A rows clamp to
// row 0 (uniform vmcnt); garbage discarded at C-stage time.
template<int EP, int AGATHER, int BM, int BN, int KSPLIT, int XSWZ = 0>
__global__ __launch_bounds__(256, 4)
void gemm_k(const __hip_bfloat16* __restrict__ A,
            const __hip_bfloat16* __restrict__ Bt,
            const float* __restrict__ bias,
            int M, int N, int K,
            __hip_bfloat16* __restrict__ oq, __hip_bfloat16* __restrict__ okk,
            __hip_bfloat16* __restrict__ ov,
            float* __restrict__ of, const float* __restrict__ resid,
            __hip_bfloat16* __restrict__ oh,
            int win_base, int m_base)
{
    constexpr int LPW = (BM + BN) / 64;     // DMA issues per wave per K-step
    constexpr int FI = BM / 32;
    constexpr int FJ = BN / 32;
    constexpr int ASZ = BM * 32;            // shorts per A buffer
    constexpr int BSZ = BN * 32;
    __shared__ __align__(16) unsigned short lds[4 * (ASZ + BSZ)];
    unsigned short* Asb = lds;
    unsigned short* Bsb = lds + 4 * ASZ;

    int tid = threadIdx.x;
    int wave = tid >> 6, lane = tid & 63;
    int n16 = lane & 15, quad = lane >> 4;
    int wrr = wave >> 1, wcc = wave & 1;

    int bx = blockIdx.x, by = blockIdx.y;
    if constexpr (XSWZ) {
        // bijective XCD swizzle: HW places block lin on XCD lin%8; give that
        // XCD the contiguous run [pos ...] of x-fastest tile ids.
        int gx = gridDim.x, gy = gridDim.y;
        int lin = by * gx + bx;
        int nwg = gx * gy;
        int qq = nwg >> 3, rr8 = nwg & 7;
        int xcd = lin & 7, pos = lin >> 3;
        int swz = (xcd < rr8) ? (xcd * (qq + 1) + pos)
                              : (rr8 * (qq + 1) + (xcd - rr8) * qq + pos);
        bx = swz % gx;
        by = swz / gx;
    }
    int bm = by * BM;                  // transposed grid
    int bn = bx * BN;
    int kz = (KSPLIT > 1) ? blockIdx.z : 0;
    int kseg = K / KSPLIT;

    int srow = tid >> 2;
    int q4 = tid & 3;
    int skoff = (q4 ^ ((srow >> 1) & 3)) << 3;   // swizzled source granule

    const unsigned short* Au = (const unsigned short*)A;
    const unsigned short* Bu = (const unsigned short*)Bt;

    int src0 = 0, src1 = 0;
    if (AGATHER) {
        int s0 = gather_src(bm + srow, M, win_base);
        src0 = s0 >= 0 ? s0 : 0;
        if (BM == 128) {
            int s1 = gather_src(bm + 64 + srow, M, win_base);
            src1 = s1 >= 0 ? s1 : 0;
        }
    } else {
        int m0 = bm + srow;
        src0 = m0 < M ? m0 : 0;
        if (BM == 128) { int m1 = bm + 64 + srow; src1 = m1 < M ? m1 : 0; }
    }

    const unsigned short* ap0 = Au + (size_t)src0 * K + kz * kseg + skoff;
    const unsigned short* ap1 = Au + (size_t)src1 * K + kz * kseg + skoff;
    const unsigned short* bp0 = Bu + (size_t)(bn + srow) * K + kz * kseg + skoff;
    const unsigned short* bp1 = Bu + (size_t)(bn + 64 + srow) * K + kz * kseg + skoff;

    auto stage = [&](int kt, int b) {
        size_t ko = (size_t)kt * 32;
        gload16(ap0 + ko, Asb + b * ASZ + wave * 512);
        if constexpr (BM == 128) gload16(ap1 + ko, Asb + b * ASZ + 2048 + wave * 512);
        gload16(bp0 + ko, Bsb + b * BSZ + wave * 512);
        if constexpr (BN == 128) gload16(bp1 + ko, Bsb + b * BSZ + 2048 + wave * 512);
    };

    floatx4 acc[FI][FJ] = {};
    int xr = (n16 >> 1) & 3;
    int nt = kseg >> 5;

    // prologue: 3 tiles in flight
    stage(0, 0);
    if (nt > 1) stage(1, 1);
    if (nt > 2) stage(2, 2);

    for (int t = 0; t < nt; ++t) {
        int cur = t & 3;
        int ahead = nt - 1 - t;
        if (ahead >= 2) {
            if constexpr (LPW == 4)      asm volatile("s_waitcnt vmcnt(8)" ::: "memory");
            else if constexpr (LPW == 3) asm volatile("s_waitcnt vmcnt(6)" ::: "memory");
            else                         asm volatile("s_waitcnt vmcnt(4)" ::: "memory");
        } else if (ahead == 1) {
            if constexpr (LPW == 4)      asm volatile("s_waitcnt vmcnt(4)" ::: "memory");
            else if constexpr (LPW == 3) asm volatile("s_waitcnt vmcnt(3)" ::: "memory");
            else                         asm volatile("s_waitcnt vmcnt(2)" ::: "memory");
        } else {
            asm volatile("s_waitcnt vmcnt(0)" ::: "memory");
        }
        __builtin_amdgcn_s_barrier();          // tile t visible to all waves
        if (t + 3 < nt) stage(t + 3, (t + 3) & 3);
        short8 af[FI], bf[FJ];
        #pragma unroll
        for (int i = 0; i < FI; ++i) {
            int ra = wrr * (BM / 2) + i * 16 + n16;
            af[i] = *(const short8*)&Asb[cur * ASZ + ra * 32 + ((quad ^ xr) << 3)];
        }
        #pragma unroll
        for (int j = 0; j < FJ; ++j) {
            int rb = wcc * (BN / 2) + j * 16 + n16;
            bf[j] = *(const short8*)&Bsb[cur * BSZ + rb * 32 + ((quad ^ xr) << 3)];
        }
        #pragma unroll
        for (int i = 0; i < FI; ++i)
            #pragma unroll
            for (int j = 0; j < FJ; ++j)
                acc[i][j] = __builtin_amdgcn_mfma_f32_16x16x32_bf16(
                    af[i], bf[j], acc[i][j], 0, 0, 0);
        asm volatile("s_waitcnt lgkmcnt(0)" ::: "memory");  // reads retired
    }

    int rbase = bm + wrr * (BM / 2) + quad * 4;
    int cbase = bn + wcc * (BN / 2) + n16;

    if constexpr (EP == 0 || EP == 2) {
        // ---- C-tile through LDS: coalesced 128B row-half stores ----
        constexpr int CLD = BN + 8;            // padded bf16 row stride
        __syncthreads();                       // staging ring no longer needed
        unsigned short* Cs = lds;
        int ruseW[FI * 4];
        if (EP == 0) {
            #pragma unroll
            for (int i = 0; i < FI; ++i)
                #pragma unroll
                for (int r = 0; r < 4; ++r)
                    ruseW[i * 4 + r] = gather_src(rbase + i * 16 + r, M, win_base) >= 0;
        }
        #pragma unroll
        for (int j = 0; j < FJ; ++j) {
            int col_l = wcc * (BN / 2) + j * 16 + n16;
            float bcol = bias[bn + col_l];
            #pragma unroll
            for (int i = 0; i < FI; ++i) {
                #pragma unroll
                for (int r = 0; r < 4; ++r) {
                    int row_l = wrr * (BM / 2) + i * 16 + quad * 4 + r;
                    float val = acc[i][j][r] + bcol;
                    float vv;
                    if (EP == 0) {
                        vv = ruseW[i * 4 + r] ? val : bcol;
                    } else {
                        vv = 0.5f * val * (1.0f + erff(val * 0.70710678118654752f));
                    }
                    Cs[row_l * CLD + col_l] = f2bu(vv);
                }
            }
        }
        __syncthreads();
        #pragma unroll
        for (int rep = 0; rep < (BM * (BN / 64)) / 256; ++rep) {
            int idx = rep * 256 + tid;
            int row_l = idx / (BN / 64);
            int half = idx - row_l * (BN / 64);
            int m = bm + row_l;
            if (m < M) {
                unsigned short* srcu = &Cs[row_l * CLD + half * 64];
                unsigned short* dstu;
                if (EP == 0) {
                    int lwin = m / TOK, tok = m - lwin * TOK;
                    int colg = bn + half * 64;
                    int which = colg / HS;
                    int head = (colg - which * HS) >> 6;
                    __hip_bfloat16* dstp = (which == 0) ? oq : ((which == 1) ? okk : ov);
                    dstu = (unsigned short*)dstp +
                           ((size_t)(lwin * NHEADS + head) * TOK + tok) * HD;
                } else {
                    dstu = (unsigned short*)oh + (size_t)m * N + bn + half * 64;
                }
                #pragma unroll
                for (int s = 0; s < 8; ++s)
                    *(uint4*)(dstu + s * 8) = *(const uint4*)(srcu + s * 8);
            }
        }
    } else {
        // ---- direct epilogues (EP1 proj fp32 +resid, EP3 accumulate) ----
        int rowoff[FI * 4];
        int ruse[FI * 4];
        #pragma unroll
        for (int i = 0; i < FI; ++i) {
            #pragma unroll
            for (int r = 0; r < 4; ++r) {
                int ii = i * 4 + r;
                int row = rbase + i * 16 + r;
                if (EP == 1) {
                    int lwin = row / TOK, tok = row - lwin * TOK;
                    int win = win_base + lwin;
                    int bb = win / WIN_PER_B, rr2 = win - bb * WIN_PER_B;
                    int wi = rr2 / NSIDE, wj = rr2 - wi * NSIDE;
                    int ti = tok / WSZ, tj = tok - ti * WSZ;
                    int h = wi * WSZ + ti, w = wj * WSZ + tj;
                    ruse[ii] = (h < HWDIM) && (w < HWDIM);
                    rowoff[ii] = ((bb * HWDIM + h) * HWDIM + w) * HS;
                } else {
                    rowoff[ii] = (m_base + row) * HS;
                    ruse[ii] = 1;
                }
            }
        }
        #pragma unroll
        for (int j = 0; j < FJ; ++j) {
            int col = cbase + j * 16;
            float bcol = bias[col];
            if (EP == 3 && KSPLIT > 1 && kz != 0) bcol = 0.0f;
            #pragma unroll
            for (int i = 0; i < FI; ++i) {
                #pragma unroll
                for (int r = 0; r < 4; ++r) {
                    int ii = i * 4 + r;
                    int row = rbase + i * 16 + r;
                    if (row >= M) continue;
                    float val = acc[i][j][r] + bcol;
                    if (EP == 1) {
                        if (ruse[ii]) {
                            size_t idx = (size_t)rowoff[ii] + col;
                            of[idx] = resid[idx] + val;
                        }
                    } else {
                        size_t idx = (size_t)rowoff[ii] + col;
                        if (KSPLIT > 1) {
                            unsafeAtomicAdd(&of[idx], val);
                        } else {
                            of[idx] += val;
                        }
                    }
                }
            }
        }
    }
}

// ---- MFMA attention. One block per (local window, head); 4 waves.
// rel-pos bias folded INTO the QK^T MFMA via extended K (one-hot cols):
// S[q][k] = (0.125 q)·k + qe·ke where ke = [one-hot(ki), one-hot(kj), 0..]
// (32 extra dims staged once in KE[208][40]) and qe[64+i] = rel[q][ti+13-i],
// qe[78+j] = relw[q][tj+13-j] (8 scalar LDS reads/lane/q-tile instead of the
// old 104-read bias gather). Scale bookkeeping: q-frags x0.125 (exact pow2),
// rel tables x8 at btab build -> rel stays unscaled, QK gets 1/sqrt(d).
// Ks stride 72, Vt stride 232, KE stride 40 (all 2-way/free). LDS 81472 B
// -> 2 blocks/CU. Ks reads for pad rows 196..207 overflow into Vt: finite
// bf16 garbage; KE pad rows staged zero; masked in S (n16>=4 of nt=12).
__global__ __launch_bounds__(256)
void attn_k(const __hip_bfloat16* __restrict__ qb, const __hip_bfloat16* __restrict__ kb,
            const __hip_bfloat16* __restrict__ vb,
            const float* __restrict__ rph, const float* __restrict__ rpw,
            __hip_bfloat16* __restrict__ ao)
{
    __shared__ __align__(16) unsigned short lds[40736];
    unsigned short* Ks = lds;            // [196][72] bf16
    unsigned short* Vt = lds + 14112;    // [64][232] bf16 (cols 196..231 zero)
    unsigned short* KE = lds + 28960;    // [208][40] bf16 one-hot extension
    unsigned short* scr = lds + 37280;   // 4 x 864

    int bid = blockIdx.x;
    int lwin = bid / NHEADS, head = bid - lwin * NHEADS;
    size_t base = (size_t)(lwin * NHEADS + head) * TOK * HD;
    const unsigned short* q = (const unsigned short*)qb + base;
    const unsigned short* k = (const unsigned short*)kb + base;
    const unsigned short* v = (const unsigned short*)vb + base;

    int tid = threadIdx.x;
    int wave = tid >> 6, lane = tid & 63;
    int n16 = lane & 15, quad = lane >> 4;

    // rel tables x8 (compensates the 0.125-scaled q in the rel MFMA)
    short8 btab[4][2];
    #pragma unroll
    for (int nt = 0; nt < 4; ++nt) {
        int n = nt * 16 + n16;
        #pragma unroll
        for (int kh = 0; kh < 2; ++kh) {
            short8 f = {0, 0, 0, 0, 0, 0, 0, 0};
            if (n < 54) {
                const float* src = (n < 27) ? (rph + (size_t)n * HD)
                                            : (rpw + (size_t)(n - 27) * HD);
                const float4* s4 = (const float4*)(src + kh * 32 + quad * 8);
                float4 a = s4[0], b = s4[1];
                f[0] = (short)f2bu(a.x * 8.0f); f[1] = (short)f2bu(a.y * 8.0f);
                f[2] = (short)f2bu(a.z * 8.0f); f[3] = (short)f2bu(a.w * 8.0f);
                f[4] = (short)f2bu(b.x * 8.0f); f[5] = (short)f2bu(b.y * 8.0f);
                f[6] = (short)f2bu(b.z * 8.0f); f[7] = (short)f2bu(b.w * 8.0f);
            }
            btab[nt][kh] = f;
        }
    }

    // ---- stage K: 196 rows x 64 bf16 (stride 72), coalesced uint4 ----
    for (int idx = tid; idx < 1568; idx += 256) {
        int row = idx >> 3, q8 = (idx & 7) << 3;
        *(uint4*)&Ks[row * 72 + q8] = *(const uint4*)(k + (size_t)row * HD + q8);
    }
    // ---- stage V transposed: coalesced uint4 row loads, scalar LDS writes ----
    for (int s = tid; s < 1568; s += 256) {
        int row = s >> 3, d8 = (s & 7) << 3;
        uint4 vv = *(const uint4*)(v + (size_t)row * HD + d8);
        const unsigned short* p = (const unsigned short*)&vv;
        #pragma unroll
        for (int e = 0; e < 8; ++e)
            Vt[(d8 + e) * 232 + row] = p[e];
    }
    for (int s = tid; s < 64 * 9; s += 256) {    // zero cols 196..231
        int r = s / 9, c = 196 + (s - r * 9) * 4;
        uint2 z = {0u, 0u};
        *(uint2*)&Vt[r * 232 + c] = z;
    }
    // ---- stage KE one-hot: rows 0..195 = [1@ki | 1@14+kj | 0 pad]; 196..207 = 0
    for (int krow = tid; krow < 208; krow += 256) {
        int ki = krow / WSZ, kj = krow - ki * WSZ;
        int valid = krow < TOK;
        #pragma unroll
        for (int c = 0; c < 32; ++c) {
            unsigned short vv = 0;
            if (valid && (c == ki || c == 14 + kj)) vv = 0x3F80;  // bf16 1.0
            KE[krow * 40 + c] = vv;
        }
    }
    __syncthreads();

    unsigned short* myscr = &scr[wave * 864];
    int rl0 = quad * 4;

    for (int qt = wave; qt < 13; qt += 4) {
        int qrow = qt * 16 + n16;
        int qr = qrow < 196 ? qrow : 195;

        // load q frags and scale x0.125 (exact: pow2 exponent shift)
        short8 raw0 = *(const short8*)(q + (size_t)qr * HD + quad * 8);
        short8 raw1 = *(const short8*)(q + (size_t)qr * HD + 32 + quad * 8);
        short8 qf0, qf1;
        #pragma unroll
        for (int e = 0; e < 8; ++e) {
            qf0[e] = (short)f2bu(bf2f((unsigned short)raw0[e]) * 0.125f);
            qf1[e] = (short)f2bu(bf2f((unsigned short)raw1[e]) * 0.125f);
        }

        // rel bias via MFMA: rel[16 rows][54 cols] -> scr (unscaled: q/8 * 8tab)
        #pragma unroll
        for (int nt = 0; nt < 4; ++nt) {
            floatx4 cr = {0.f, 0.f, 0.f, 0.f};
            cr = __builtin_amdgcn_mfma_f32_16x16x32_bf16(qf0, btab[nt][0], cr, 0, 0, 0);
            cr = __builtin_amdgcn_mfma_f32_16x16x32_bf16(qf1, btab[nt][1], cr, 0, 0, 0);
            int c = nt * 16 + n16;
            if (c < 54) {
                #pragma unroll
                for (int r = 0; r < 4; ++r)
                    myscr[(rl0 + r) * 54 + c] = f2bu(cr[r]);
            }
        }

        // build extended-q fragment: qe[64+d] picked from this lane's rel row
        int ti_l = qr / WSZ, tj_l = qr - ti_l * WSZ;
        short8 qf2;
        #pragma unroll
        for (int e = 0; e < 8; ++e) {
            int d = quad * 8 + e;
            int idx_i = n16 * 54 + ti_l + 13 - d;
            int idx_j = n16 * 54 + 40 + tj_l - (d - 14);
            int idx = (d < 14) ? idx_i : idx_j;
            unsigned short vv = (d < 28) ? myscr[idx] : (unsigned short)0;
            qf2[e] = (short)vv;
        }

        // S = 0.125*QK^T + bias (3 k-steps: K 0..63 + one-hot 64..95)
        floatx4 S[13];
        __builtin_amdgcn_s_setprio(1);
        #pragma unroll
        for (int nt = 0; nt < 13; ++nt) {
            int kr = nt * 16 + n16;
            short8 kf0 = *(const short8*)&Ks[kr * 72 + quad * 8];
            short8 kf1 = *(const short8*)&Ks[kr * 72 + 32 + quad * 8];
            short8 kf2 = *(const short8*)&KE[kr * 40 + quad * 8];
            floatx4 a = {0.f, 0.f, 0.f, 0.f};
            a = __builtin_amdgcn_mfma_f32_16x16x32_bf16(qf0, kf0, a, 0, 0, 0);
            a = __builtin_amdgcn_mfma_f32_16x16x32_bf16(qf1, kf1, a, 0, 0, 0);
            a = __builtin_amdgcn_mfma_f32_16x16x32_bf16(qf2, kf2, a, 0, 0, 0);
            S[nt] = a;
        }
        __builtin_amdgcn_s_setprio(0);

        if (n16 >= 4) {
            #pragma unroll
            for (int r = 0; r < 4; ++r) S[12][r] = -1e30f;
        }

        float mxr[4] = {-3e30f, -3e30f, -3e30f, -3e30f};
        #pragma unroll
        for (int nt = 0; nt < 13; ++nt)
            #pragma unroll
            for (int r = 0; r < 4; ++r) mxr[r] = fmaxf(mxr[r], S[nt][r]);
        #pragma unroll
        for (int m = 1; m <= 8; m <<= 1)
            #pragma unroll
            for (int r = 0; r < 4; ++r) mxr[r] = fmaxf(mxr[r], __shfl_xor(mxr[r], m, 64));
        float sum[4] = {0.f, 0.f, 0.f, 0.f};
        #pragma unroll
        for (int nt = 0; nt < 13; ++nt)
            #pragma unroll
            for (int r = 0; r < 4; ++r) {
                float e = __expf(S[nt][r] - mxr[r]);
                S[nt][r] = e;
                sum[r] += e;
            }
        #pragma unroll
        for (int m = 1; m <= 8; m <<= 1)
            #pragma unroll
            for (int r = 0; r < 4; ++r) sum[r] += __shfl_xor(sum[r], m, 64);
        float inv[4];
        #pragma unroll
        for (int r = 0; r < 4; ++r) inv[r] = 1.0f / sum[r];

        floatx4 O[4] = {{0.f,0.f,0.f,0.f},{0.f,0.f,0.f,0.f},{0.f,0.f,0.f,0.f},{0.f,0.f,0.f,0.f}};
        __builtin_amdgcn_s_setprio(1);
        #pragma unroll
        for (int ks = 0; ks < 7; ++ks) {
            #pragma unroll
            for (int r = 0; r < 4; ++r) {
                myscr[(rl0 + r) * 40 + n16] = f2bu(S[2 * ks][r] * inv[r]);
                myscr[(rl0 + r) * 40 + 16 + n16] =
                    (2 * ks + 1 < 13) ? f2bu(S[2 * ks + 1][r] * inv[r]) : (unsigned short)0;
            }
            short8 pf = *(const short8*)&myscr[n16 * 40 + quad * 8];
            #pragma unroll
            for (int nt4 = 0; nt4 < 4; ++nt4) {
                short8 vf = *(const short8*)&Vt[(nt4 * 16 + n16) * 232 + ks * 32 + quad * 8];
                O[nt4] = __builtin_amdgcn_mfma_f32_16x16x32_bf16(pf, vf, O[nt4], 0, 0, 0);
            }
        }
        __builtin_amdgcn_s_setprio(0);

        #pragma unroll
        for (int nt4 = 0; nt4 < 4; ++nt4) {
            int d = nt4 * 16 + n16;
            #pragma unroll
            for (int r = 0; r < 4; ++r) {
                int row = qt * 16 + rl0 + r;
                if (row < 196) {
                    ao[((size_t)(lwin * TOK + row)) * HS + head * HD + d] =
                        __float2bfloat16(O[nt4][r]);
                }
            }
        }
    }
}

extern "C" void kernel_launch(void* const* d_in, const int* in_sizes, int n_in,
                              void* d_out, int out_size, void* d_ws, size_t ws_size,
                              hipStream_t stream)
{
    const float* x      = (const float*)d_in[0];
    const float* ln1_g  = (const float*)d_in[1];
    const float* ln1_b  = (const float*)d_in[2];
    const float* qkv_w  = (const float*)d_in[3];
    const float* qkv_b  = (const float*)d_in[4];
    const float* proj_w = (const float*)d_in[5];
    const float* proj_b = (const float*)d_in[6];
    const float* rph    = (const float*)d_in[7];
    const float* rpw    = (const float*)d_in[8];
    const float* ln2_g  = (const float*)d_in[9];
    const float* ln2_b  = (const float*)d_in[10];
    const float* mlp_w1 = (const float*)d_in[11];
    const float* mlp_b1 = (const float*)d_in[12];
    const float* mlp_w2 = (const float*)d_in[13];
    const float* mlp_b2 = (const float*)d_in[14];
    float* out = (float*)d_out;

    char* ws = (char*)d_ws;
    __hip_bfloat16* wqkv  = (__hip_bfloat16*)(ws + 0);          // [2304][768]
    __hip_bfloat16* wproj = (__hip_bfloat16*)(ws + 3538944);    // [768][768]
    __hip_bfloat16* wm1   = (__hip_bfloat16*)(ws + 4718592);    // [3072][768]
    __hip_bfloat16* wm2   = (__hip_bfloat16*)(ws + 9437184);    // [768][3072]
    __hip_bfloat16* ybuf  = (__hip_bfloat16*)(ws + 14155776);   // 32768x768
    char* R2 = ws + 64487424;
    __hip_bfloat16* hid = (__hip_bfloat16*)(R2);

    // ---- runtime-tiered attention chunking by workspace size ----
    // per-window q/k/v/ao footprint: 12*196*64*2 = 301056 B per buffer
    const size_t PERWIN = 301056;
    int nwin_chunk, nchunks;
    if (ws_size >= 64487424ull + 4ull * 200 * PERWIN) {         // ~292 MB
        nwin_chunk = 200; nchunks = 1;
    } else if (ws_size >= 64487424ull + 4ull * 100 * PERWIN) {  // ~177 MB
        nwin_chunk = 100; nchunks = 2;
    } else {
        nwin_chunk = 25; nchunks = 8;
    }
    size_t bufsz = (size_t)nwin_chunk * PERWIN;
    __hip_bfloat16* qc = (__hip_bfloat16*)(R2);
    __hip_bfloat16* kc = (__hip_bfloat16*)(R2 + bufsz);
    __hip_bfloat16* vc = (__hip_bfloat16*)(R2 + 2 * bufsz);
    __hip_bfloat16* ao = (__hip_bfloat16*)(R2 + 3 * bufsz);

    // MLP chunking: 2 chunks of 16384 (hid slice 100 MB L3-resident,
    // full-round grids); fallback 4 x 8192
    int mlpch, nmlp;
    if (ws_size >= 64487424ull + (size_t)16384 * 3072 * 2) {
        mlpch = 16384; nmlp = 2;
    } else {
        mlpch = 8192; nmlp = 4;
    }

    cvt_t_k<<<dim3(72, 24), 256, 0, stream>>>(qkv_w,  wqkv,  768, 2304);
    cvt_t_k<<<dim3(24, 24), 256, 0, stream>>>(proj_w, wproj, 768, 768);
    cvt_t_k<<<dim3(96, 24), 256, 0, stream>>>(mlp_w1, wm1,   768, 3072);
    cvt_t_k<<<dim3(24, 96), 256, 0, stream>>>(mlp_w2, wm2,  3072, 768);

    ln_k<<<dim3(8192), 256, 0, stream>>>(x, ln1_g, ln1_b, ybuf);

    for (int c = 0; c < nchunks; ++c) {
        int M = nwin_chunk * TOK;
        int wb = c * nwin_chunk;
        gemm_k<0, 1, 128, 128, 1, 1><<<dim3(18, (M + 127) / 128), 256, 0, stream>>>(
            ybuf, wqkv, qkv_b, M, 2304, 768,
            qc, kc, vc, nullptr, nullptr, nullptr, wb, 0);
        attn_k<<<dim3(nwin_chunk * NHEADS), 256, 0, stream>>>(
            qc, kc, vc, rph, rpw, ao);
        gemm_k<1, 0, 128, 128, 1><<<dim3(6, (M + 127) / 128), 256, 0, stream>>>(
            ao, wproj, proj_b, M, 768, 768,
            nullptr, nullptr, nullptr, out, x, nullptr, wb, 0);
    }

    ln_k<<<dim3(8192), 256, 0, stream>>>(out, ln2_g, ln2_b, ybuf);

    for (int mc = 0; mc < nmlp; ++mc) {
        gemm_k<2, 0, 128, 128, 1><<<dim3(24, mlpch / 128), 256, 0, stream>>>(
            ybuf + (size_t)mc * mlpch * HS, wm1, mlp_b1, mlpch, 3072, 768,
            nullptr, nullptr, nullptr, nullptr, nullptr, hid, 0, 0);
        gemm_k<3, 0, 128, 64, 1><<<dim3(12, mlpch / 128), 256, 0, stream>>>(
            hid, wm2, mlp_b2, mlpch, 768, 3072,
            nullptr, nullptr, nullptr, out, nullptr, nullptr, 0, mc * mlpch);
    }
}

// Round 20
// 1386.814 us; speedup vs baseline: 1.0933x; 1.0126x over previous
//
#include <hip/hip_runtime.h>
#include <hip/hip_bf16.h>
#include <math.h>

// SAM vision layer: LN1 -> windowed attention (decomposed rel-pos bias) -> proj
// + residual -> LN2 -> MLP(GELU exact) -> residual.
// B=8, H=W=64, HS=768, NH=12, HD=64, WS=14 -> 200 windows x 196 tokens.

#define HS 768
#define NHEADS 12
#define HD 64
#define WSZ 14
#define TOK 196
#define HWDIM 64
#define NSIDE 5
#define WIN_PER_B 25

typedef __attribute__((ext_vector_type(8))) short short8;
typedef __attribute__((ext_vector_type(4))) float floatx4;
typedef __attribute__((ext_vector_type(4))) unsigned short ushort4v;

__device__ __forceinline__ float bf2f(unsigned short u) {
    union { unsigned int i; float f; } w; w.i = ((unsigned int)u) << 16; return w.f;
}
__device__ __forceinline__ unsigned short f2bu(float f) {
    __hip_bfloat16 h = __float2bfloat16(f);
    return *(unsigned short*)&h;
}

// async global->LDS, 16B per lane. LDS dest must be wave-uniform base;
// HW writes lane l at base + l*16. Global src is per-lane.
__device__ __forceinline__ void gload16(const void* g, void* l) {
    __builtin_amdgcn_global_load_lds(
        (const __attribute__((address_space(1))) void*)g,
        (__attribute__((address_space(3))) void*)l, 16, 0, 0);
}

// window gather: map output row m (chunk-local) -> source spatial row, or -1
__device__ __forceinline__ int gather_src(int m, int M, int win_base) {
    if (m >= M) return -1;
    int lwin = m / TOK, tok = m - lwin * TOK;
    int win = win_base + lwin;
    int bb = win / WIN_PER_B, r = win - bb * WIN_PER_B;
    int wi = r / NSIDE, wj = r - wi * NSIDE;
    int ti = tok / WSZ, tj = tok - ti * WSZ;
    int h = wi * WSZ + ti, w = wj * WSZ + tj;
    if (h < HWDIM && w < HWDIM) return (bb * HWDIM + h) * HWDIM + w;
    return -1;
}

// ---- fp32 -> bf16 transposed convert via LDS tile: src[K][N] -> dst[N][K].
__global__ __launch_bounds__(256)
void cvt_t_k(const float* __restrict__ src, __hip_bfloat16* __restrict__ dst,
             int K, int N) {
    __shared__ float t[32][33];
    int n0 = blockIdx.x * 32, k0 = blockIdx.y * 32;
    int tc = threadIdx.x & 31, tr8 = threadIdx.x >> 5;   // tr8: 0..7
    #pragma unroll
    for (int i = 0; i < 4; ++i) {
        int r = tr8 + i * 8;
        t[r][tc] = src[(size_t)(k0 + r) * N + n0 + tc];
    }
    __syncthreads();
    #pragma unroll
    for (int i = 0; i < 4; ++i) {
        int r = tr8 + i * 8;
        dst[(size_t)(n0 + r) * K + k0 + tc] = __float2bfloat16(t[tc][r]);
    }
}

// ---- LayerNorm over HS=768: one WAVE per row, float4 loads, shuffle-only
// reduce (no LDS, no barrier). 256 threads = 4 rows/block; grid = rows/4.
__global__ __launch_bounds__(256)
void ln_k(const float* __restrict__ x, const float* __restrict__ g,
          const float* __restrict__ b, __hip_bfloat16* __restrict__ y) {
    int wave = threadIdx.x >> 6, lane = threadIdx.x & 63;
    int row = blockIdx.x * 4 + wave;
    const float4* xr = (const float4*)(x + (size_t)row * HS);
    float4 a0 = xr[lane], a1 = xr[lane + 64], a2 = xr[lane + 128];
    float s = a0.x + a0.y + a0.z + a0.w + a1.x + a1.y + a1.z + a1.w
            + a2.x + a2.y + a2.z + a2.w;
    float q = a0.x*a0.x + a0.y*a0.y + a0.z*a0.z + a0.w*a0.w
            + a1.x*a1.x + a1.y*a1.y + a1.z*a1.z + a1.w*a1.w
            + a2.x*a2.x + a2.y*a2.y + a2.z*a2.z + a2.w*a2.w;
    #pragma unroll
    for (int off = 32; off > 0; off >>= 1) {
        s += __shfl_down(s, off, 64);
        q += __shfl_down(q, off, 64);
    }
    s = __shfl(s, 0, 64);
    q = __shfl(q, 0, 64);
    float mu = s * (1.0f / HS);
    float var = q * (1.0f / HS) - mu * mu;
    float rstd = rsqrtf(var + 1e-6f);
    const float4* g4 = (const float4*)g;
    const float4* b4 = (const float4*)b;
    unsigned short* yr = (unsigned short*)y + (size_t)row * HS;
    float4 av[3] = {a0, a1, a2};
    #pragma unroll
    for (int c = 0; c < 3; ++c) {
        float4 gv = g4[lane + 64 * c], bv = b4[lane + 64 * c];
        float4 a = av[c];
        ushort4v o;
        o[0] = f2bu((a.x - mu) * rstd * gv.x + bv.x);
        o[1] = f2bu((a.y - mu) * rstd * gv.y + bv.y);
        o[2] = f2bu((a.z - mu) * rstd * gv.z + bv.z);
        o[3] = f2bu((a.w - mu) * rstd * gv.w + bv.w);
        *(ushort4v*)&yr[(lane + 64 * c) * 4] = o;
    }
}

// ---- bf16 MFMA GEMM, BM x BN tile, BK=32, 4 waves (2x2), wave tile
// (BM/2)x(BN/2). RING-deep LDS ring with counted vmcnt (up to RING-2 tiles
// stay in flight across the barrier). Both-sides granule XOR swizzle (0 bank
// conflicts, r5). Transposed grid (blockIdx.x = col panel) keeps the A
// row-panel L2-hot. XSWZ=1: bijective XCD swizzle (m204) -- each XCD gets a
// CONTIGUOUS run of x-fastest tile ids (QKV FETCH 267->186 MB, r19).
// RING=3 -> 48 KB LDS -> 3 blocks/CU (vs 2 at RING=4): TLP for the
// barrier-synced phases. EP0/EP2 epilogues stage the C-tile in LDS and
// write 128B-contiguous segments. Gather-invalid A rows clamp to row 0
// (uniform vmcnt); garbage discarded at C-stage time.
template<int EP, int AGATHER, int BM, int BN, int KSPLIT, int XSWZ = 0, int RING = 4>
__global__ __launch_bounds__(256, 4)
void gemm_k(const __hip_bfloat16* __restrict__ A,
            const __hip_bfloat16* __restrict__ Bt,
            const float* __restrict__ bias,
            int M, int N, int K,
            __hip_bfloat16* __restrict__ oq, __hip_bfloat16* __restrict__ okk,
            __hip_bfloat16* __restrict__ ov,
            float* __restrict__ of, const float* __restrict__ resid,
            __hip_bfloat16* __restrict__ oh,
            int win_base, int m_base)
{
    constexpr int LPW = (BM + BN) / 64;     // DMA issues per wave per K-step
    constexpr int FI = BM / 32;
    constexpr int FJ = BN / 32;
    constexpr int ASZ = BM * 32;            // shorts per A buffer
    constexpr int BSZ = BN * 32;
    __shared__ __align__(16) unsigned short lds[RING * (ASZ + BSZ)];
    unsigned short* Asb = lds;
    unsigned short* Bsb = lds + RING * ASZ;

    int tid = threadIdx.x;
    int wave = tid >> 6, lane = tid & 63;
    int n16 = lane & 15, quad = lane >> 4;
    int wrr = wave >> 1, wcc = wave & 1;

    int bx = blockIdx.x, by = blockIdx.y;
    if constexpr (XSWZ) {
        // bijective XCD swizzle: HW places block lin on XCD lin%8; give that
        // XCD the contiguous run [pos ...] of x-fastest tile ids.
        int gx = gridDim.x, gy = gridDim.y;
        int lin = by * gx + bx;
        int nwg = gx * gy;
        int qq = nwg >> 3, rr8 = nwg & 7;
        int xcd = lin & 7, pos = lin >> 3;
        int swz = (xcd < rr8) ? (xcd * (qq + 1) + pos)
                              : (rr8 * (qq + 1) + (xcd - rr8) * qq + pos);
        bx = swz % gx;
        by = swz / gx;
    }
    int bm = by * BM;                  // transposed grid
    int bn = bx * BN;
    int kz = (KSPLIT > 1) ? blockIdx.z : 0;
    int kseg = K / KSPLIT;

    int srow = tid >> 2;
    int q4 = tid & 3;
    int skoff = (q4 ^ ((srow >> 1) & 3)) << 3;   // swizzled source granule

    const unsigned short* Au = (const unsigned short*)A;
    const unsigned short* Bu = (const unsigned short*)Bt;

    int src0 = 0, src1 = 0;
    if (AGATHER) {
        int s0 = gather_src(bm + srow, M, win_base);
        src0 = s0 >= 0 ? s0 : 0;
        if (BM == 128) {
            int s1 = gather_src(bm + 64 + srow, M, win_base);
            src1 = s1 >= 0 ? s1 : 0;
        }
    } else {
        int m0 = bm + srow;
        src0 = m0 < M ? m0 : 0;
        if (BM == 128) { int m1 = bm + 64 + srow; src1 = m1 < M ? m1 : 0; }
    }

    const unsigned short* ap0 = Au + (size_t)src0 * K + kz * kseg + skoff;
    const unsigned short* ap1 = Au + (size_t)src1 * K + kz * kseg + skoff;
    const unsigned short* bp0 = Bu + (size_t)(bn + srow) * K + kz * kseg + skoff;
    const unsigned short* bp1 = Bu + (size_t)(bn + 64 + srow) * K + kz * kseg + skoff;

    auto stage = [&](int kt, int b) {
        size_t ko = (size_t)kt * 32;
        gload16(ap0 + ko, Asb + b * ASZ + wave * 512);
        if constexpr (BM == 128) gload16(ap1 + ko, Asb + b * ASZ + 2048 + wave * 512);
        gload16(bp0 + ko, Bsb + b * BSZ + wave * 512);
        if constexpr (BN == 128) gload16(bp1 + ko, Bsb + b * BSZ + 2048 + wave * 512);
    };

    floatx4 acc[FI][FJ] = {};
    int xr = (n16 >> 1) & 3;
    int nt = kseg >> 5;

    // prologue: RING-1 tiles in flight
    stage(0, 0);
    if (nt > 1) stage(1, 1);
    if (RING > 3 && nt > 2) stage(2, 2);

    int cur = 0;
    for (int t = 0; t < nt; ++t) {
        int ahead = nt - 1 - t;
        // allowed outstanding = min(RING-2, ahead) * LPW
        if (RING >= 4 && ahead >= 2) {
            if constexpr (LPW == 4)      asm volatile("s_waitcnt vmcnt(8)" ::: "memory");
            else if constexpr (LPW == 3) asm volatile("s_waitcnt vmcnt(6)" ::: "memory");
            else                         asm volatile("s_waitcnt vmcnt(4)" ::: "memory");
        } else if (ahead >= 1) {
            if constexpr (LPW == 4)      asm volatile("s_waitcnt vmcnt(4)" ::: "memory");
            else if constexpr (LPW == 3) asm volatile("s_waitcnt vmcnt(3)" ::: "memory");
            else                         asm volatile("s_waitcnt vmcnt(2)" ::: "memory");
        } else {
            asm volatile("s_waitcnt vmcnt(0)" ::: "memory");
        }
        __builtin_amdgcn_s_barrier();          // tile t visible to all waves
        if (t + RING - 1 < nt) {
            int nb = cur + RING - 1; if (nb >= RING) nb -= RING;
            stage(t + RING - 1, nb);
        }
        short8 af[FI], bf[FJ];
        #pragma unroll
        for (int i = 0; i < FI; ++i) {
            int ra = wrr * (BM / 2) + i * 16 + n16;
            af[i] = *(const short8*)&Asb[cur * ASZ + ra * 32 + ((quad ^ xr) << 3)];
        }
        #pragma unroll
        for (int j = 0; j < FJ; ++j) {
            int rb = wcc * (BN / 2) + j * 16 + n16;
            bf[j] = *(const short8*)&Bsb[cur * BSZ + rb * 32 + ((quad ^ xr) << 3)];
        }
        #pragma unroll
        for (int i = 0; i < FI; ++i)
            #pragma unroll
            for (int j = 0; j < FJ; ++j)
                acc[i][j] = __builtin_amdgcn_mfma_f32_16x16x32_bf16(
                    af[i], bf[j], acc[i][j], 0, 0, 0);
        asm volatile("s_waitcnt lgkmcnt(0)" ::: "memory");  // reads retired
        cur += 1; if (cur >= RING) cur -= RING;
    }

    int rbase = bm + wrr * (BM / 2) + quad * 4;
    int cbase = bn + wcc * (BN / 2) + n16;

    if constexpr (EP == 0 || EP == 2) {
        // ---- C-tile through LDS: coalesced 128B row-half stores ----
        constexpr int CLD = BN + 8;            // padded bf16 row stride
        __syncthreads();                       // staging ring no longer needed
        unsigned short* Cs = lds;
        int ruseW[FI * 4];
        if (EP == 0) {
            #pragma unroll
            for (int i = 0; i < FI; ++i)
                #pragma unroll
                for (int r = 0; r < 4; ++r)
                    ruseW[i * 4 + r] = gather_src(rbase + i * 16 + r, M, win_base) >= 0;
        }
        #pragma unroll
        for (int j = 0; j < FJ; ++j) {
            int col_l = wcc * (BN / 2) + j * 16 + n16;
            float bcol = bias[bn + col_l];
            #pragma unroll
            for (int i = 0; i < FI; ++i) {
                #pragma unroll
                for (int r = 0; r < 4; ++r) {
                    int row_l = wrr * (BM / 2) + i * 16 + quad * 4 + r;
                    float val = acc[i][j][r] + bcol;
                    float vv;
                    if (EP == 0) {
                        vv = ruseW[i * 4 + r] ? val : bcol;
                    } else {
                        vv = 0.5f * val * (1.0f + erff(val * 0.70710678118654752f));
                    }
                    Cs[row_l * CLD + col_l] = f2bu(vv);
                }
            }
        }
        __syncthreads();
        #pragma unroll
        for (int rep = 0; rep < (BM * (BN / 64)) / 256; ++rep) {
            int idx = rep * 256 + tid;
            int row_l = idx / (BN / 64);
            int half = idx - row_l * (BN / 64);
            int m = bm + row_l;
            if (m < M) {
                unsigned short* srcu = &Cs[row_l * CLD + half * 64];
                unsigned short* dstu;
                if (EP == 0) {
                    int lwin = m / TOK, tok = m - lwin * TOK;
                    int colg = bn + half * 64;
                    int which = colg / HS;
                    int head = (colg - which * HS) >> 6;
                    __hip_bfloat16* dstp = (which == 0) ? oq : ((which == 1) ? okk : ov);
                    dstu = (unsigned short*)dstp +
                           ((size_t)(lwin * NHEADS + head) * TOK + tok) * HD;
                } else {
                    dstu = (unsigned short*)oh + (size_t)m * N + bn + half * 64;
                }
                #pragma unroll
                for (int s = 0; s < 8; ++s)
                    *(uint4*)(dstu + s * 8) = *(const uint4*)(srcu + s * 8);
            }
        }
    } else {
        // ---- direct epilogues (EP1 proj fp32 +resid, EP3 accumulate) ----
        int rowoff[FI * 4];
        int ruse[FI * 4];
        #pragma unroll
        for (int i = 0; i < FI; ++i) {
            #pragma unroll
            for (int r = 0; r < 4; ++r) {
                int ii = i * 4 + r;
                int row = rbase + i * 16 + r;
                if (EP == 1) {
                    int lwin = row / TOK, tok = row - lwin * TOK;
                    int win = win_base + lwin;
                    int bb = win / WIN_PER_B, rr2 = win - bb * WIN_PER_B;
                    int wi = rr2 / NSIDE, wj = rr2 - wi * NSIDE;
                    int ti = tok / WSZ, tj = tok - ti * WSZ;
                    int h = wi * WSZ + ti, w = wj * WSZ + tj;
                    ruse[ii] = (h < HWDIM) && (w < HWDIM);
                    rowoff[ii] = ((bb * HWDIM + h) * HWDIM + w) * HS;
                } else {
                    rowoff[ii] = (m_base + row) * HS;
                    ruse[ii] = 1;
                }
            }
        }
        #pragma unroll
        for (int j = 0; j < FJ; ++j) {
            int col = cbase + j * 16;
            float bcol = bias[col];
            if (EP == 3 && KSPLIT > 1 && kz != 0) bcol = 0.0f;
            #pragma unroll
            for (int i = 0; i < FI; ++i) {
                #pragma unroll
                for (int r = 0; r < 4; ++r) {
                    int ii = i * 4 + r;
                    int row = rbase + i * 16 + r;
                    if (row >= M) continue;
                    float val = acc[i][j][r] + bcol;
                    if (EP == 1) {
                        if (ruse[ii]) {
                            size_t idx = (size_t)rowoff[ii] + col;
                            of[idx] = resid[idx] + val;
                        }
                    } else {
                        size_t idx = (size_t)rowoff[ii] + col;
                        if (KSPLIT > 1) {
                            unsafeAtomicAdd(&of[idx], val);
                        } else {
                            of[idx] += val;
                        }
                    }
                }
            }
        }
    }
}

// ---- MFMA attention. One block per (local window, head); 4 waves.
// rel-pos bias folded INTO the QK^T MFMA via extended K (one-hot cols):
// S[q][k] = (0.125 q)·k + qe·ke where ke = [one-hot(ki), one-hot(kj), 0..]
// (32 extra dims staged once in KE[208][40]) and qe[64+i] = rel[q][ti+13-i],
// qe[78+j] = relw[q][tj+13-j] (8 scalar LDS reads/lane/q-tile instead of the
// old 104-read bias gather). Scale bookkeeping: q-frags x0.125 (exact pow2),
// rel tables x8 at btab build -> rel stays unscaled, QK gets 1/sqrt(d).
// Ks stride 72, Vt stride 232, KE stride 40 (all 2-way/free). LDS 81472 B
// -> 2 blocks/CU. Ks reads for pad rows 196..207 overflow into Vt: finite
// bf16 garbage; KE pad rows staged zero; masked in S (n16>=4 of nt=12).
__global__ __launch_bounds__(256)
void attn_k(const __hip_bfloat16* __restrict__ qb, const __hip_bfloat16* __restrict__ kb,
            const __hip_bfloat16* __restrict__ vb,
            const float* __restrict__ rph, const float* __restrict__ rpw,
            __hip_bfloat16* __restrict__ ao)
{
    __shared__ __align__(16) unsigned short lds[40736];
    unsigned short* Ks = lds;            // [196][72] bf16
    unsigned short* Vt = lds + 14112;    // [64][232] bf16 (cols 196..231 zero)
    unsigned short* KE = lds + 28960;    // [208][40] bf16 one-hot extension
    unsigned short* scr = lds + 37280;   // 4 x 864

    int bid = blockIdx.x;
    int lwin = bid / NHEADS, head = bid - lwin * NHEADS;
    size_t base = (size_t)(lwin * NHEADS + head) * TOK * HD;
    const unsigned short* q = (const unsigned short*)qb + base;
    const unsigned short* k = (const unsigned short*)kb + base;
    const unsigned short* v = (const unsigned short*)vb + base;

    int tid = threadIdx.x;
    int wave = tid >> 6, lane = tid & 63;
    int n16 = lane & 15, quad = lane >> 4;

    // rel tables x8 (compensates the 0.125-scaled q in the rel MFMA)
    short8 btab[4][2];
    #pragma unroll
    for (int nt = 0; nt < 4; ++nt) {
        int n = nt * 16 + n16;
        #pragma unroll
        for (int kh = 0; kh < 2; ++kh) {
            short8 f = {0, 0, 0, 0, 0, 0, 0, 0};
            if (n < 54) {
                const float* src = (n < 27) ? (rph + (size_t)n * HD)
                                            : (rpw + (size_t)(n - 27) * HD);
                const float4* s4 = (const float4*)(src + kh * 32 + quad * 8);
                float4 a = s4[0], b = s4[1];
                f[0] = (short)f2bu(a.x * 8.0f); f[1] = (short)f2bu(a.y * 8.0f);
                f[2] = (short)f2bu(a.z * 8.0f); f[3] = (short)f2bu(a.w * 8.0f);
                f[4] = (short)f2bu(b.x * 8.0f); f[5] = (short)f2bu(b.y * 8.0f);
                f[6] = (short)f2bu(b.z * 8.0f); f[7] = (short)f2bu(b.w * 8.0f);
            }
            btab[nt][kh] = f;
        }
    }

    // ---- stage K: 196 rows x 64 bf16 (stride 72), coalesced uint4 ----
    for (int idx = tid; idx < 1568; idx += 256) {
        int row = idx >> 3, q8 = (idx & 7) << 3;
        *(uint4*)&Ks[row * 72 + q8] = *(const uint4*)(k + (size_t)row * HD + q8);
    }
    // ---- stage V transposed: coalesced uint4 row loads, scalar LDS writes ----
    for (int s = tid; s < 1568; s += 256) {
        int row = s >> 3, d8 = (s & 7) << 3;
        uint4 vv = *(const uint4*)(v + (size_t)row * HD + d8);
        const unsigned short* p = (const unsigned short*)&vv;
        #pragma unroll
        for (int e = 0; e < 8; ++e)
            Vt[(d8 + e) * 232 + row] = p[e];
    }
    for (int s = tid; s < 64 * 9; s += 256) {    // zero cols 196..231
        int r = s / 9, c = 196 + (s - r * 9) * 4;
        uint2 z = {0u, 0u};
        *(uint2*)&Vt[r * 232 + c] = z;
    }
    // ---- stage KE one-hot: rows 0..195 = [1@ki | 1@14+kj | 0 pad]; 196..207 = 0
    for (int krow = tid; krow < 208; krow += 256) {
        int ki = krow / WSZ, kj = krow - ki * WSZ;
        int valid = krow < TOK;
        #pragma unroll
        for (int c = 0; c < 32; ++c) {
            unsigned short vv = 0;
            if (valid && (c == ki || c == 14 + kj)) vv = 0x3F80;  // bf16 1.0
            KE[krow * 40 + c] = vv;
        }
    }
    __syncthreads();

    unsigned short* myscr = &scr[wave * 864];
    int rl0 = quad * 4;

    for (int qt = wave; qt < 13; qt += 4) {
        int qrow = qt * 16 + n16;
        int qr = qrow < 196 ? qrow : 195;

        // load q frags and scale x0.125 (exact: pow2 exponent shift)
        short8 raw0 = *(const short8*)(q + (size_t)qr * HD + quad * 8);
        short8 raw1 = *(const short8*)(q + (size_t)qr * HD + 32 + quad * 8);
        short8 qf0, qf1;
        #pragma unroll
        for (int e = 0; e < 8; ++e) {
            qf0[e] = (short)f2bu(bf2f((unsigned short)raw0[e]) * 0.125f);
            qf1[e] = (short)f2bu(bf2f((unsigned short)raw1[e]) * 0.125f);
        }

        // rel bias via MFMA: rel[16 rows][54 cols] -> scr (unscaled: q/8 * 8tab)
        #pragma unroll
        for (int nt = 0; nt < 4; ++nt) {
            floatx4 cr = {0.f, 0.f, 0.f, 0.f};
            cr = __builtin_amdgcn_mfma_f32_16x16x32_bf16(qf0, btab[nt][0], cr, 0, 0, 0);
            cr = __builtin_amdgcn_mfma_f32_16x16x32_bf16(qf1, btab[nt][1], cr, 0, 0, 0);
            int c = nt * 16 + n16;
            if (c < 54) {
                #pragma unroll
                for (int r = 0; r < 4; ++r)
                    myscr[(rl0 + r) * 54 + c] = f2bu(cr[r]);
            }
        }

        // build extended-q fragment: qe[64+d] picked from this lane's rel row
        int ti_l = qr / WSZ, tj_l = qr - ti_l * WSZ;
        short8 qf2;
        #pragma unroll
        for (int e = 0; e < 8; ++e) {
            int d = quad * 8 + e;
            int idx_i = n16 * 54 + ti_l + 13 - d;
            int idx_j = n16 * 54 + 40 + tj_l - (d - 14);
            int idx = (d < 14) ? idx_i : idx_j;
            unsigned short vv = (d < 28) ? myscr[idx] : (unsigned short)0;
            qf2[e] = (short)vv;
        }

        // S = 0.125*QK^T + bias (3 k-steps: K 0..63 + one-hot 64..95)
        floatx4 S[13];
        __builtin_amdgcn_s_setprio(1);
        #pragma unroll
        for (int nt = 0; nt < 13; ++nt) {
            int kr = nt * 16 + n16;
            short8 kf0 = *(const short8*)&Ks[kr * 72 + quad * 8];
            short8 kf1 = *(const short8*)&Ks[kr * 72 + 32 + quad * 8];
            short8 kf2 = *(const short8*)&KE[kr * 40 + quad * 8];
            floatx4 a = {0.f, 0.f, 0.f, 0.f};
            a = __builtin_amdgcn_mfma_f32_16x16x32_bf16(qf0, kf0, a, 0, 0, 0);
            a = __builtin_amdgcn_mfma_f32_16x16x32_bf16(qf1, kf1, a, 0, 0, 0);
            a = __builtin_amdgcn_mfma_f32_16x16x32_bf16(qf2, kf2, a, 0, 0, 0);
            S[nt] = a;
        }
        __builtin_amdgcn_s_setprio(0);

        if (n16 >= 4) {
            #pragma unroll
            for (int r = 0; r < 4; ++r) S[12][r] = -1e30f;
        }

        float mxr[4] = {-3e30f, -3e30f, -3e30f, -3e30f};
        #pragma unroll
        for (int nt = 0; nt < 13; ++nt)
            #pragma unroll
            for (int r = 0; r < 4; ++r) mxr[r] = fmaxf(mxr[r], S[nt][r]);
        #pragma unroll
        for (int m = 1; m <= 8; m <<= 1)
            #pragma unroll
            for (int r = 0; r < 4; ++r) mxr[r] = fmaxf(mxr[r], __shfl_xor(mxr[r], m, 64));
        float sum[4] = {0.f, 0.f, 0.f, 0.f};
        #pragma unroll
        for (int nt = 0; nt < 13; ++nt)
            #pragma unroll
            for (int r = 0; r < 4; ++r) {
                float e = __expf(S[nt][r] - mxr[r]);
                S[nt][r] = e;
                sum[r] += e;
            }
        #pragma unroll
        for (int m = 1; m <= 8; m <<= 1)
            #pragma unroll
            for (int r = 0; r < 4; ++r) sum[r] += __shfl_xor(sum[r], m, 64);
        float inv[4];
        #pragma unroll
        for (int r = 0; r < 4; ++r) inv[r] = 1.0f / sum[r];

        floatx4 O[4] = {{0.f,0.f,0.f,0.f},{0.f,0.f,0.f,0.f},{0.f,0.f,0.f,0.f},{0.f,0.f,0.f,0.f}};
        __builtin_amdgcn_s_setprio(1);
        #pragma unroll
        for (int ks = 0; ks < 7; ++ks) {
            #pragma unroll
            for (int r = 0; r < 4; ++r) {
                myscr[(rl0 + r) * 40 + n16] = f2bu(S[2 * ks][r] * inv[r]);
                myscr[(rl0 + r) * 40 + 16 + n16] =
                    (2 * ks + 1 < 13) ? f2bu(S[2 * ks + 1][r] * inv[r]) : (unsigned short)0;
            }
            short8 pf = *(const short8*)&myscr[n16 * 40 + quad * 8];
            #pragma unroll
            for (int nt4 = 0; nt4 < 4; ++nt4) {
                short8 vf = *(const short8*)&Vt[(nt4 * 16 + n16) * 232 + ks * 32 + quad * 8];
                O[nt4] = __builtin_amdgcn_mfma_f32_16x16x32_bf16(pf, vf, O[nt4], 0, 0, 0);
            }
        }
        __builtin_amdgcn_s_setprio(0);

        #pragma unroll
        for (int nt4 = 0; nt4 < 4; ++nt4) {
            int d = nt4 * 16 + n16;
            #pragma unroll
            for (int r = 0; r < 4; ++r) {
                int row = qt * 16 + rl0 + r;
                if (row < 196) {
                    ao[((size_t)(lwin * TOK + row)) * HS + head * HD + d] =
                        __float2bfloat16(O[nt4][r]);
                }
            }
        }
    }
}

extern "C" void kernel_launch(void* const* d_in, const int* in_sizes, int n_in,
                              void* d_out, int out_size, void* d_ws, size_t ws_size,
                              hipStream_t stream)
{
    const float* x      = (const float*)d_in[0];
    const float* ln1_g  = (const float*)d_in[1];
    const float* ln1_b  = (const float*)d_in[2];
    const float* qkv_w  = (const float*)d_in[3];
    const float* qkv_b  = (const float*)d_in[4];
    const float* proj_w = (const float*)d_in[5];
    const float* proj_b = (const float*)d_in[6];
    const float* rph    = (const float*)d_in[7];
    const float* rpw    = (const float*)d_in[8];
    const float* ln2_g  = (const float*)d_in[9];
    const float* ln2_b  = (const float*)d_in[10];
    const float* mlp_w1 = (const float*)d_in[11];
    const float* mlp_b1 = (const float*)d_in[12];
    const float* mlp_w2 = (const float*)d_in[13];
    const float* mlp_b2 = (const float*)d_in[14];
    float* out = (float*)d_out;

    char* ws = (char*)d_ws;
    __hip_bfloat16* wqkv  = (__hip_bfloat16*)(ws + 0);          // [2304][768]
    __hip_bfloat16* wproj = (__hip_bfloat16*)(ws + 3538944);    // [768][768]
    __hip_bfloat16* wm1   = (__hip_bfloat16*)(ws + 4718592);    // [3072][768]
    __hip_bfloat16* wm2   = (__hip_bfloat16*)(ws + 9437184);    // [768][3072]
    __hip_bfloat16* ybuf  = (__hip_bfloat16*)(ws + 14155776);   // 32768x768
    char* R2 = ws + 64487424;
    __hip_bfloat16* hid = (__hip_bfloat16*)(R2);

    // ---- runtime-tiered attention chunking by workspace size ----
    // per-window q/k/v/ao footprint: 12*196*64*2 = 301056 B per buffer
    const size_t PERWIN = 301056;
    int nwin_chunk, nchunks;
    if (ws_size >= 64487424ull + 4ull * 200 * PERWIN) {         // ~292 MB
        nwin_chunk = 200; nchunks = 1;
    } else if (ws_size >= 64487424ull + 4ull * 100 * PERWIN) {  // ~177 MB
        nwin_chunk = 100; nchunks = 2;
    } else {
        nwin_chunk = 25; nchunks = 8;
    }
    size_t bufsz = (size_t)nwin_chunk * PERWIN;
    __hip_bfloat16* qc = (__hip_bfloat16*)(R2);
    __hip_bfloat16* kc = (__hip_bfloat16*)(R2 + bufsz);
    __hip_bfloat16* vc = (__hip_bfloat16*)(R2 + 2 * bufsz);
    __hip_bfloat16* ao = (__hip_bfloat16*)(R2 + 3 * bufsz);

    // MLP chunking: 2 chunks of 16384 (hid slice 100 MB L3-resident,
    // full-round grids); fallback 4 x 8192
    int mlpch, nmlp;
    if (ws_size >= 64487424ull + (size_t)16384 * 3072 * 2) {
        mlpch = 16384; nmlp = 2;
    } else {
        mlpch = 8192; nmlp = 4;
    }

    cvt_t_k<<<dim3(72, 24), 256, 0, stream>>>(qkv_w,  wqkv,  768, 2304);
    cvt_t_k<<<dim3(24, 24), 256, 0, stream>>>(proj_w, wproj, 768, 768);
    cvt_t_k<<<dim3(96, 24), 256, 0, stream>>>(mlp_w1, wm1,   768, 3072);
    cvt_t_k<<<dim3(24, 96), 256, 0, stream>>>(mlp_w2, wm2,  3072, 768);

    ln_k<<<dim3(8192), 256, 0, stream>>>(x, ln1_g, ln1_b, ybuf);

    for (int c = 0; c < nchunks; ++c) {
        int M = nwin_chunk * TOK;
        int wb = c * nwin_chunk;
        gemm_k<0, 1, 128, 128, 1, 1, 3><<<dim3(18, (M + 127) / 128), 256, 0, stream>>>(
            ybuf, wqkv, qkv_b, M, 2304, 768,
            qc, kc, vc, nullptr, nullptr, nullptr, wb, 0);
        attn_k<<<dim3(nwin_chunk * NHEADS), 256, 0, stream>>>(
            qc, kc, vc, rph, rpw, ao);
        gemm_k<1, 0, 128, 128, 1><<<dim3(6, (M + 127) / 128), 256, 0, stream>>>(
            ao, wproj, proj_b, M, 768, 768,
            nullptr, nullptr, nullptr, out, x, nullptr, wb, 0);
    }

    ln_k<<<dim3(8192), 256, 0, stream>>>(out, ln2_g, ln2_b, ybuf);

    for (int mc = 0; mc < nmlp; ++mc) {
        gemm_k<2, 0, 128, 128, 1><<<dim3(24, mlpch / 128), 256, 0, stream>>>(
            ybuf + (size_t)mc * mlpch * HS, wm1, mlp_b1, mlpch, 3072, 768,
            nullptr, nullptr, nullptr, nullptr, nullptr, hid, 0, 0);
        gemm_k<3, 0, 128, 64, 1><<<dim3(12, mlpch / 128), 256, 0, stream>>>(
            hid, wm2, mlp_b2, mlpch, 768, 3072,
            nullptr, nullptr, nullptr, out, nullptr, nullptr, 0, mc * mlpch);
    }
}

// Round 21
// 1327.143 us; speedup vs baseline: 1.1425x; 1.0450x over previous
//
#include <hip/hip_runtime.h>
#include <hip/hip_bf16.h>
#include <math.h>

// SAM vision layer: LN1 -> windowed attention (decomposed rel-pos bias) -> proj
// + residual -> LN2 -> MLP(GELU exact) -> residual.
// B=8, H=W=64, HS=768, NH=12, HD=64, WS=14 -> 200 windows x 196 tokens.

#define HS 768
#define NHEADS 12
#define HD 64
#define WSZ 14
#define TOK 196
#define HWDIM 64
#define NSIDE 5
#define WIN_PER_B 25

typedef __attribute__((ext_vector_type(8))) short short8;
typedef __attribute__((ext_vector_type(4))) float floatx4;
typedef __attribute__((ext_vector_type(4))) unsigned short ushort4v;

__device__ __forceinline__ float bf2f(unsigned short u) {
    union { unsigned int i; float f; } w; w.i = ((unsigned int)u) << 16; return w.f;
}
__device__ __forceinline__ unsigned short f2bu(float f) {
    __hip_bfloat16 h = __float2bfloat16(f);
    return *(unsigned short*)&h;
}

// async global->LDS, 16B per lane. LDS dest must be wave-uniform base;
// HW writes lane l at base + l*16. Global src is per-lane.
__device__ __forceinline__ void gload16(const void* g, void* l) {
    __builtin_amdgcn_global_load_lds(
        (const __attribute__((address_space(1))) void*)g,
        (__attribute__((address_space(3))) void*)l, 16, 0, 0);
}

// window gather: map output row m (chunk-local) -> source spatial row, or -1
__device__ __forceinline__ int gather_src(int m, int M, int win_base) {
    if (m >= M) return -1;
    int lwin = m / TOK, tok = m - lwin * TOK;
    int win = win_base + lwin;
    int bb = win / WIN_PER_B, r = win - bb * WIN_PER_B;
    int wi = r / NSIDE, wj = r - wi * NSIDE;
    int ti = tok / WSZ, tj = tok - ti * WSZ;
    int h = wi * WSZ + ti, w = wj * WSZ + tj;
    if (h < HWDIM && w < HWDIM) return (bb * HWDIM + h) * HWDIM + w;
    return -1;
}

// ---- fp32 -> bf16 transposed convert via LDS tile: src[K][N] -> dst[N][K].
__global__ __launch_bounds__(256)
void cvt_t_k(const float* __restrict__ src, __hip_bfloat16* __restrict__ dst,
             int K, int N) {
    __shared__ float t[32][33];
    int n0 = blockIdx.x * 32, k0 = blockIdx.y * 32;
    int tc = threadIdx.x & 31, tr8 = threadIdx.x >> 5;   // tr8: 0..7
    #pragma unroll
    for (int i = 0; i < 4; ++i) {
        int r = tr8 + i * 8;
        t[r][tc] = src[(size_t)(k0 + r) * N + n0 + tc];
    }
    __syncthreads();
    #pragma unroll
    for (int i = 0; i < 4; ++i) {
        int r = tr8 + i * 8;
        dst[(size_t)(n0 + r) * K + k0 + tc] = __float2bfloat16(t[tc][r]);
    }
}

// ---- LayerNorm over HS=768: one WAVE per row, float4 loads, shuffle-only
// reduce (no LDS, no barrier). 256 threads = 4 rows/block; grid = rows/4.
__global__ __launch_bounds__(256)
void ln_k(const float* __restrict__ x, const float* __restrict__ g,
          const float* __restrict__ b, __hip_bfloat16* __restrict__ y) {
    int wave = threadIdx.x >> 6, lane = threadIdx.x & 63;
    int row = blockIdx.x * 4 + wave;
    const float4* xr = (const float4*)(x + (size_t)row * HS);
    float4 a0 = xr[lane], a1 = xr[lane + 64], a2 = xr[lane + 128];
    float s = a0.x + a0.y + a0.z + a0.w + a1.x + a1.y + a1.z + a1.w
            + a2.x + a2.y + a2.z + a2.w;
    float q = a0.x*a0.x + a0.y*a0.y + a0.z*a0.z + a0.w*a0.w
            + a1.x*a1.x + a1.y*a1.y + a1.z*a1.z + a1.w*a1.w
            + a2.x*a2.x + a2.y*a2.y + a2.z*a2.z + a2.w*a2.w;
    #pragma unroll
    for (int off = 32; off > 0; off >>= 1) {
        s += __shfl_down(s, off, 64);
        q += __shfl_down(q, off, 64);
    }
    s = __shfl(s, 0, 64);
    q = __shfl(q, 0, 64);
    float mu = s * (1.0f / HS);
    float var = q * (1.0f / HS) - mu * mu;
    float rstd = rsqrtf(var + 1e-6f);
    const float4* g4 = (const float4*)g;
    const float4* b4 = (const float4*)b;
    unsigned short* yr = (unsigned short*)y + (size_t)row * HS;
    float4 av[3] = {a0, a1, a2};
    #pragma unroll
    for (int c = 0; c < 3; ++c) {
        float4 gv = g4[lane + 64 * c], bv = b4[lane + 64 * c];
        float4 a = av[c];
        ushort4v o;
        o[0] = f2bu((a.x - mu) * rstd * gv.x + bv.x);
        o[1] = f2bu((a.y - mu) * rstd * gv.y + bv.y);
        o[2] = f2bu((a.z - mu) * rstd * gv.z + bv.z);
        o[3] = f2bu((a.w - mu) * rstd * gv.w + bv.w);
        *(ushort4v*)&yr[(lane + 64 * c) * 4] = o;
    }
}

// ---- bf16 MFMA GEMM, BM x BN tile, BK=32, 4 waves (2x2), wave tile
// (BM/2)x(BN/2). RING-deep LDS ring with counted vmcnt (up to RING-2 tiles
// stay in flight across the barrier). Both-sides granule XOR swizzle (0 bank
// conflicts, r5). Transposed grid (blockIdx.x = col panel) keeps the A
// row-panel L2-hot. XSWZ=1: bijective XCD swizzle (m204) -- each XCD gets a
// CONTIGUOUS run of x-fastest tile ids (QKV FETCH 267->186 MB, r19).
// RING=3 -> 48 KB LDS at 128x128 -> 3 blocks/CU (vs 2 at RING=4): verified
// +10% on QKV (r20: occ 21->30.5%, 235->215 us). EP0/EP2 epilogues stage
// the C-tile in LDS and write 128B-contiguous segments. Gather-invalid A
// rows clamp to row 0 (uniform vmcnt); garbage discarded at C-stage time.
template<int EP, int AGATHER, int BM, int BN, int KSPLIT, int XSWZ = 0, int RING = 3>
__global__ __launch_bounds__(256, 4)
void gemm_k(const __hip_bfloat16* __restrict__ A,
            const __hip_bfloat16* __restrict__ Bt,
            const float* __restrict__ bias,
            int M, int N, int K,
            __hip_bfloat16* __restrict__ oq, __hip_bfloat16* __restrict__ okk,
            __hip_bfloat16* __restrict__ ov,
            float* __restrict__ of, const float* __restrict__ resid,
            __hip_bfloat16* __restrict__ oh,
            int win_base, int m_base)
{
    constexpr int LPW = (BM + BN) / 64;     // DMA issues per wave per K-step
    constexpr int FI = BM / 32;
    constexpr int FJ = BN / 32;
    constexpr int ASZ = BM * 32;            // shorts per A buffer
    constexpr int BSZ = BN * 32;
    __shared__ __align__(16) unsigned short lds[RING * (ASZ + BSZ)];
    unsigned short* Asb = lds;
    unsigned short* Bsb = lds + RING * ASZ;

    int tid = threadIdx.x;
    int wave = tid >> 6, lane = tid & 63;
    int n16 = lane & 15, quad = lane >> 4;
    int wrr = wave >> 1, wcc = wave & 1;

    int bx = blockIdx.x, by = blockIdx.y;
    if constexpr (XSWZ) {
        // bijective XCD swizzle: HW places block lin on XCD lin%8; give that
        // XCD the contiguous run [pos ...] of x-fastest tile ids.
        int gx = gridDim.x, gy = gridDim.y;
        int lin = by * gx + bx;
        int nwg = gx * gy;
        int qq = nwg >> 3, rr8 = nwg & 7;
        int xcd = lin & 7, pos = lin >> 3;
        int swz = (xcd < rr8) ? (xcd * (qq + 1) + pos)
                              : (rr8 * (qq + 1) + (xcd - rr8) * qq + pos);
        bx = swz % gx;
        by = swz / gx;
    }
    int bm = by * BM;                  // transposed grid
    int bn = bx * BN;
    int kz = (KSPLIT > 1) ? blockIdx.z : 0;
    int kseg = K / KSPLIT;

    int srow = tid >> 2;
    int q4 = tid & 3;
    int skoff = (q4 ^ ((srow >> 1) & 3)) << 3;   // swizzled source granule

    const unsigned short* Au = (const unsigned short*)A;
    const unsigned short* Bu = (const unsigned short*)Bt;

    int src0 = 0, src1 = 0;
    if (AGATHER) {
        int s0 = gather_src(bm + srow, M, win_base);
        src0 = s0 >= 0 ? s0 : 0;
        if (BM == 128) {
            int s1 = gather_src(bm + 64 + srow, M, win_base);
            src1 = s1 >= 0 ? s1 : 0;
        }
    } else {
        int m0 = bm + srow;
        src0 = m0 < M ? m0 : 0;
        if (BM == 128) { int m1 = bm + 64 + srow; src1 = m1 < M ? m1 : 0; }
    }

    const unsigned short* ap0 = Au + (size_t)src0 * K + kz * kseg + skoff;
    const unsigned short* ap1 = Au + (size_t)src1 * K + kz * kseg + skoff;
    const unsigned short* bp0 = Bu + (size_t)(bn + srow) * K + kz * kseg + skoff;
    const unsigned short* bp1 = Bu + (size_t)(bn + 64 + srow) * K + kz * kseg + skoff;

    auto stage = [&](int kt, int b) {
        size_t ko = (size_t)kt * 32;
        gload16(ap0 + ko, Asb + b * ASZ + wave * 512);
        if constexpr (BM == 128) gload16(ap1 + ko, Asb + b * ASZ + 2048 + wave * 512);
        gload16(bp0 + ko, Bsb + b * BSZ + wave * 512);
        if constexpr (BN == 128) gload16(bp1 + ko, Bsb + b * BSZ + 2048 + wave * 512);
    };

    floatx4 acc[FI][FJ] = {};
    int xr = (n16 >> 1) & 3;
    int nt = kseg >> 5;

    // prologue: RING-1 tiles in flight
    stage(0, 0);
    if (nt > 1) stage(1, 1);
    if (RING > 3 && nt > 2) stage(2, 2);

    int cur = 0;
    for (int t = 0; t < nt; ++t) {
        int ahead = nt - 1 - t;
        // allowed outstanding = min(RING-2, ahead) * LPW
        if (RING >= 4 && ahead >= 2) {
            if constexpr (LPW == 4)      asm volatile("s_waitcnt vmcnt(8)" ::: "memory");
            else if constexpr (LPW == 3) asm volatile("s_waitcnt vmcnt(6)" ::: "memory");
            else                         asm volatile("s_waitcnt vmcnt(4)" ::: "memory");
        } else if (ahead >= 1) {
            if constexpr (LPW == 4)      asm volatile("s_waitcnt vmcnt(4)" ::: "memory");
            else if constexpr (LPW == 3) asm volatile("s_waitcnt vmcnt(3)" ::: "memory");
            else                         asm volatile("s_waitcnt vmcnt(2)" ::: "memory");
        } else {
            asm volatile("s_waitcnt vmcnt(0)" ::: "memory");
        }
        __builtin_amdgcn_s_barrier();          // tile t visible to all waves
        if (t + RING - 1 < nt) {
            int nb = cur + RING - 1; if (nb >= RING) nb -= RING;
            stage(t + RING - 1, nb);
        }
        short8 af[FI], bf[FJ];
        #pragma unroll
        for (int i = 0; i < FI; ++i) {
            int ra = wrr * (BM / 2) + i * 16 + n16;
            af[i] = *(const short8*)&Asb[cur * ASZ + ra * 32 + ((quad ^ xr) << 3)];
        }
        #pragma unroll
        for (int j = 0; j < FJ; ++j) {
            int rb = wcc * (BN / 2) + j * 16 + n16;
            bf[j] = *(const short8*)&Bsb[cur * BSZ + rb * 32 + ((quad ^ xr) << 3)];
        }
        #pragma unroll
        for (int i = 0; i < FI; ++i)
            #pragma unroll
            for (int j = 0; j < FJ; ++j)
                acc[i][j] = __builtin_amdgcn_mfma_f32_16x16x32_bf16(
                    af[i], bf[j], acc[i][j], 0, 0, 0);
        asm volatile("s_waitcnt lgkmcnt(0)" ::: "memory");  // reads retired
        cur += 1; if (cur >= RING) cur -= RING;
    }

    int rbase = bm + wrr * (BM / 2) + quad * 4;
    int cbase = bn + wcc * (BN / 2) + n16;

    if constexpr (EP == 0 || EP == 2) {
        // ---- C-tile through LDS: coalesced 128B row-half stores ----
        constexpr int CLD = BN + 8;            // padded bf16 row stride
        __syncthreads();                       // staging ring no longer needed
        unsigned short* Cs = lds;
        int ruseW[FI * 4];
        if (EP == 0) {
            #pragma unroll
            for (int i = 0; i < FI; ++i)
                #pragma unroll
                for (int r = 0; r < 4; ++r)
                    ruseW[i * 4 + r] = gather_src(rbase + i * 16 + r, M, win_base) >= 0;
        }
        #pragma unroll
        for (int j = 0; j < FJ; ++j) {
            int col_l = wcc * (BN / 2) + j * 16 + n16;
            float bcol = bias[bn + col_l];
            #pragma unroll
            for (int i = 0; i < FI; ++i) {
                #pragma unroll
                for (int r = 0; r < 4; ++r) {
                    int row_l = wrr * (BM / 2) + i * 16 + quad * 4 + r;
                    float val = acc[i][j][r] + bcol;
                    float vv;
                    if (EP == 0) {
                        vv = ruseW[i * 4 + r] ? val : bcol;
                    } else {
                        vv = 0.5f * val * (1.0f + erff(val * 0.70710678118654752f));
                    }
                    Cs[row_l * CLD + col_l] = f2bu(vv);
                }
            }
        }
        __syncthreads();
        #pragma unroll
        for (int rep = 0; rep < (BM * (BN / 64)) / 256; ++rep) {
            int idx = rep * 256 + tid;
            int row_l = idx / (BN / 64);
            int half = idx - row_l * (BN / 64);
            int m = bm + row_l;
            if (m < M) {
                unsigned short* srcu = &Cs[row_l * CLD + half * 64];
                unsigned short* dstu;
                if (EP == 0) {
                    int lwin = m / TOK, tok = m - lwin * TOK;
                    int colg = bn + half * 64;
                    int which = colg / HS;
                    int head = (colg - which * HS) >> 6;
                    __hip_bfloat16* dstp = (which == 0) ? oq : ((which == 1) ? okk : ov);
                    dstu = (unsigned short*)dstp +
                           ((size_t)(lwin * NHEADS + head) * TOK + tok) * HD;
                } else {
                    dstu = (unsigned short*)oh + (size_t)m * N + bn + half * 64;
                }
                #pragma unroll
                for (int s = 0; s < 8; ++s)
                    *(uint4*)(dstu + s * 8) = *(const uint4*)(srcu + s * 8);
            }
        }
    } else {
        // ---- direct epilogues (EP1 proj fp32 +resid, EP3 accumulate) ----
        int rowoff[FI * 4];
        int ruse[FI * 4];
        #pragma unroll
        for (int i = 0; i < FI; ++i) {
            #pragma unroll
            for (int r = 0; r < 4; ++r) {
                int ii = i * 4 + r;
                int row = rbase + i * 16 + r;
                if (EP == 1) {
                    int lwin = row / TOK, tok = row - lwin * TOK;
                    int win = win_base + lwin;
                    int bb = win / WIN_PER_B, rr2 = win - bb * WIN_PER_B;
                    int wi = rr2 / NSIDE, wj = rr2 - wi * NSIDE;
                    int ti = tok / WSZ, tj = tok - ti * WSZ;
                    int h = wi * WSZ + ti, w = wj * WSZ + tj;
                    ruse[ii] = (h < HWDIM) && (w < HWDIM);
                    rowoff[ii] = ((bb * HWDIM + h) * HWDIM + w) * HS;
                } else {
                    rowoff[ii] = (m_base + row) * HS;
                    ruse[ii] = 1;
                }
            }
        }
        #pragma unroll
        for (int j = 0; j < FJ; ++j) {
            int col = cbase + j * 16;
            float bcol = bias[col];
            if (EP == 3 && KSPLIT > 1 && kz != 0) bcol = 0.0f;
            #pragma unroll
            for (int i = 0; i < FI; ++i) {
                #pragma unroll
                for (int r = 0; r < 4; ++r) {
                    int ii = i * 4 + r;
                    int row = rbase + i * 16 + r;
                    if (row >= M) continue;
                    float val = acc[i][j][r] + bcol;
                    if (EP == 1) {
                        if (ruse[ii]) {
                            size_t idx = (size_t)rowoff[ii] + col;
                            of[idx] = resid[idx] + val;
                        }
                    } else {
                        size_t idx = (size_t)rowoff[ii] + col;
                        if (KSPLIT > 1) {
                            unsafeAtomicAdd(&of[idx], val);
                        } else {
                            of[idx] += val;
                        }
                    }
                }
            }
        }
    }
}

// ---- MFMA attention. One block per (local window, head); 4 waves.
// rel-pos bias folded INTO the QK^T MFMA via extended K (one-hot cols):
// S[q][k] = (0.125 q)·k + qe·ke where ke = [one-hot(ki), one-hot(kj), 0..]
// (32 extra dims staged once in KE[208][40]) and qe[64+i] = rel[q][ti+13-i],
// qe[78+j] = relw[q][tj+13-j] (8 scalar LDS reads/lane/q-tile instead of the
// old 104-read bias gather). Scale bookkeeping: q-frags x0.125 (exact pow2),
// rel tables x8 at btab build -> rel stays unscaled, QK gets 1/sqrt(d).
// Ks stride 72, Vt stride 232, KE stride 40 (all 2-way/free). LDS 81472 B
// -> 2 blocks/CU. Ks reads for pad rows 196..207 overflow into Vt: finite
// bf16 garbage; KE pad rows staged zero; masked in S (n16>=4 of nt=12).
__global__ __launch_bounds__(256)
void attn_k(const __hip_bfloat16* __restrict__ qb, const __hip_bfloat16* __restrict__ kb,
            const __hip_bfloat16* __restrict__ vb,
            const float* __restrict__ rph, const float* __restrict__ rpw,
            __hip_bfloat16* __restrict__ ao)
{
    __shared__ __align__(16) unsigned short lds[40736];
    unsigned short* Ks = lds;            // [196][72] bf16
    unsigned short* Vt = lds + 14112;    // [64][232] bf16 (cols 196..231 zero)
    unsigned short* KE = lds + 28960;    // [208][40] bf16 one-hot extension
    unsigned short* scr = lds + 37280;   // 4 x 864

    int bid = blockIdx.x;
    int lwin = bid / NHEADS, head = bid - lwin * NHEADS;
    size_t base = (size_t)(lwin * NHEADS + head) * TOK * HD;
    const unsigned short* q = (const unsigned short*)qb + base;
    const unsigned short* k = (const unsigned short*)kb + base;
    const unsigned short* v = (const unsigned short*)vb + base;

    int tid = threadIdx.x;
    int wave = tid >> 6, lane = tid & 63;
    int n16 = lane & 15, quad = lane >> 4;

    // rel tables x8 (compensates the 0.125-scaled q in the rel MFMA)
    short8 btab[4][2];
    #pragma unroll
    for (int nt = 0; nt < 4; ++nt) {
        int n = nt * 16 + n16;
        #pragma unroll
        for (int kh = 0; kh < 2; ++kh) {
            short8 f = {0, 0, 0, 0, 0, 0, 0, 0};
            if (n < 54) {
                const float* src = (n < 27) ? (rph + (size_t)n * HD)
                                            : (rpw + (size_t)(n - 27) * HD);
                const float4* s4 = (const float4*)(src + kh * 32 + quad * 8);
                float4 a = s4[0], b = s4[1];
                f[0] = (short)f2bu(a.x * 8.0f); f[1] = (short)f2bu(a.y * 8.0f);
                f[2] = (short)f2bu(a.z * 8.0f); f[3] = (short)f2bu(a.w * 8.0f);
                f[4] = (short)f2bu(b.x * 8.0f); f[5] = (short)f2bu(b.y * 8.0f);
                f[6] = (short)f2bu(b.z * 8.0f); f[7] = (short)f2bu(b.w * 8.0f);
            }
            btab[nt][kh] = f;
        }
    }

    // ---- stage K: 196 rows x 64 bf16 (stride 72), coalesced uint4 ----
    for (int idx = tid; idx < 1568; idx += 256) {
        int row = idx >> 3, q8 = (idx & 7) << 3;
        *(uint4*)&Ks[row * 72 + q8] = *(const uint4*)(k + (size_t)row * HD + q8);
    }
    // ---- stage V transposed: coalesced uint4 row loads, scalar LDS writes ----
    for (int s = tid; s < 1568; s += 256) {
        int row = s >> 3, d8 = (s & 7) << 3;
        uint4 vv = *(const uint4*)(v + (size_t)row * HD + d8);
        const unsigned short* p = (const unsigned short*)&vv;
        #pragma unroll
        for (int e = 0; e < 8; ++e)
            Vt[(d8 + e) * 232 + row] = p[e];
    }
    for (int s = tid; s < 64 * 9; s += 256) {    // zero cols 196..231
        int r = s / 9, c = 196 + (s - r * 9) * 4;
        uint2 z = {0u, 0u};
        *(uint2*)&Vt[r * 232 + c] = z;
    }
    // ---- stage KE one-hot: rows 0..195 = [1@ki | 1@14+kj | 0 pad]; 196..207 = 0
    for (int krow = tid; krow < 208; krow += 256) {
        int ki = krow / WSZ, kj = krow - ki * WSZ;
        int valid = krow < TOK;
        #pragma unroll
        for (int c = 0; c < 32; ++c) {
            unsigned short vv = 0;
            if (valid && (c == ki || c == 14 + kj)) vv = 0x3F80;  // bf16 1.0
            KE[krow * 40 + c] = vv;
        }
    }
    __syncthreads();

    unsigned short* myscr = &scr[wave * 864];
    int rl0 = quad * 4;

    for (int qt = wave; qt < 13; qt += 4) {
        int qrow = qt * 16 + n16;
        int qr = qrow < 196 ? qrow : 195;

        // load q frags and scale x0.125 (exact: pow2 exponent shift)
        short8 raw0 = *(const short8*)(q + (size_t)qr * HD + quad * 8);
        short8 raw1 = *(const short8*)(q + (size_t)qr * HD + 32 + quad * 8);
        short8 qf0, qf1;
        #pragma unroll
        for (int e = 0; e < 8; ++e) {
            qf0[e] = (short)f2bu(bf2f((unsigned short)raw0[e]) * 0.125f);
            qf1[e] = (short)f2bu(bf2f((unsigned short)raw1[e]) * 0.125f);
        }

        // rel bias via MFMA: rel[16 rows][54 cols] -> scr (unscaled: q/8 * 8tab)
        #pragma unroll
        for (int nt = 0; nt < 4; ++nt) {
            floatx4 cr = {0.f, 0.f, 0.f, 0.f};
            cr = __builtin_amdgcn_mfma_f32_16x16x32_bf16(qf0, btab[nt][0], cr, 0, 0, 0);
            cr = __builtin_amdgcn_mfma_f32_16x16x32_bf16(qf1, btab[nt][1], cr, 0, 0, 0);
            int c = nt * 16 + n16;
            if (c < 54) {
                #pragma unroll
                for (int r = 0; r < 4; ++r)
                    myscr[(rl0 + r) * 54 + c] = f2bu(cr[r]);
            }
        }

        // build extended-q fragment: qe[64+d] picked from this lane's rel row
        int ti_l = qr / WSZ, tj_l = qr - ti_l * WSZ;
        short8 qf2;
        #pragma unroll
        for (int e = 0; e < 8; ++e) {
            int d = quad * 8 + e;
            int idx_i = n16 * 54 + ti_l + 13 - d;
            int idx_j = n16 * 54 + 40 + tj_l - (d - 14);
            int idx = (d < 14) ? idx_i : idx_j;
            unsigned short vv = (d < 28) ? myscr[idx] : (unsigned short)0;
            qf2[e] = (short)vv;
        }

        // S = 0.125*QK^T + bias (3 k-steps: K 0..63 + one-hot 64..95)
        floatx4 S[13];
        __builtin_amdgcn_s_setprio(1);
        #pragma unroll
        for (int nt = 0; nt < 13; ++nt) {
            int kr = nt * 16 + n16;
            short8 kf0 = *(const short8*)&Ks[kr * 72 + quad * 8];
            short8 kf1 = *(const short8*)&Ks[kr * 72 + 32 + quad * 8];
            short8 kf2 = *(const short8*)&KE[kr * 40 + quad * 8];
            floatx4 a = {0.f, 0.f, 0.f, 0.f};
            a = __builtin_amdgcn_mfma_f32_16x16x32_bf16(qf0, kf0, a, 0, 0, 0);
            a = __builtin_amdgcn_mfma_f32_16x16x32_bf16(qf1, kf1, a, 0, 0, 0);
            a = __builtin_amdgcn_mfma_f32_16x16x32_bf16(qf2, kf2, a, 0, 0, 0);
            S[nt] = a;
        }
        __builtin_amdgcn_s_setprio(0);

        if (n16 >= 4) {
            #pragma unroll
            for (int r = 0; r < 4; ++r) S[12][r] = -1e30f;
        }

        float mxr[4] = {-3e30f, -3e30f, -3e30f, -3e30f};
        #pragma unroll
        for (int nt = 0; nt < 13; ++nt)
            #pragma unroll
            for (int r = 0; r < 4; ++r) mxr[r] = fmaxf(mxr[r], S[nt][r]);
        #pragma unroll
        for (int m = 1; m <= 8; m <<= 1)
            #pragma unroll
            for (int r = 0; r < 4; ++r) mxr[r] = fmaxf(mxr[r], __shfl_xor(mxr[r], m, 64));
        float sum[4] = {0.f, 0.f, 0.f, 0.f};
        #pragma unroll
        for (int nt = 0; nt < 13; ++nt)
            #pragma unroll
            for (int r = 0; r < 4; ++r) {
                float e = __expf(S[nt][r] - mxr[r]);
                S[nt][r] = e;
                sum[r] += e;
            }
        #pragma unroll
        for (int m = 1; m <= 8; m <<= 1)
            #pragma unroll
            for (int r = 0; r < 4; ++r) sum[r] += __shfl_xor(sum[r], m, 64);
        float inv[4];
        #pragma unroll
        for (int r = 0; r < 4; ++r) inv[r] = 1.0f / sum[r];

        floatx4 O[4] = {{0.f,0.f,0.f,0.f},{0.f,0.f,0.f,0.f},{0.f,0.f,0.f,0.f},{0.f,0.f,0.f,0.f}};
        __builtin_amdgcn_s_setprio(1);
        #pragma unroll
        for (int ks = 0; ks < 7; ++ks) {
            #pragma unroll
            for (int r = 0; r < 4; ++r) {
                myscr[(rl0 + r) * 40 + n16] = f2bu(S[2 * ks][r] * inv[r]);
                myscr[(rl0 + r) * 40 + 16 + n16] =
                    (2 * ks + 1 < 13) ? f2bu(S[2 * ks + 1][r] * inv[r]) : (unsigned short)0;
            }
            short8 pf = *(const short8*)&myscr[n16 * 40 + quad * 8];
            #pragma unroll
            for (int nt4 = 0; nt4 < 4; ++nt4) {
                short8 vf = *(const short8*)&Vt[(nt4 * 16 + n16) * 232 + ks * 32 + quad * 8];
                O[nt4] = __builtin_amdgcn_mfma_f32_16x16x32_bf16(pf, vf, O[nt4], 0, 0, 0);
            }
        }
        __builtin_amdgcn_s_setprio(0);

        #pragma unroll
        for (int nt4 = 0; nt4 < 4; ++nt4) {
            int d = nt4 * 16 + n16;
            #pragma unroll
            for (int r = 0; r < 4; ++r) {
                int row = qt * 16 + rl0 + r;
                if (row < 196) {
                    ao[((size_t)(lwin * TOK + row)) * HS + head * HD + d] =
                        __float2bfloat16(O[nt4][r]);
                }
            }
        }
    }
}

extern "C" void kernel_launch(void* const* d_in, const int* in_sizes, int n_in,
                              void* d_out, int out_size, void* d_ws, size_t ws_size,
                              hipStream_t stream)
{
    const float* x      = (const float*)d_in[0];
    const float* ln1_g  = (const float*)d_in[1];
    const float* ln1_b  = (const float*)d_in[2];
    const float* qkv_w  = (const float*)d_in[3];
    const float* qkv_b  = (const float*)d_in[4];
    const float* proj_w = (const float*)d_in[5];
    const float* proj_b = (const float*)d_in[6];
    const float* rph    = (const float*)d_in[7];
    const float* rpw    = (const float*)d_in[8];
    const float* ln2_g  = (const float*)d_in[9];
    const float* ln2_b  = (const float*)d_in[10];
    const float* mlp_w1 = (const float*)d_in[11];
    const float* mlp_b1 = (const float*)d_in[12];
    const float* mlp_w2 = (const float*)d_in[13];
    const float* mlp_b2 = (const float*)d_in[14];
    float* out = (float*)d_out;

    char* ws = (char*)d_ws;
    __hip_bfloat16* wqkv  = (__hip_bfloat16*)(ws + 0);          // [2304][768]
    __hip_bfloat16* wproj = (__hip_bfloat16*)(ws + 3538944);    // [768][768]
    __hip_bfloat16* wm1   = (__hip_bfloat16*)(ws + 4718592);    // [3072][768]
    __hip_bfloat16* wm2   = (__hip_bfloat16*)(ws + 9437184);    // [768][3072]
    __hip_bfloat16* ybuf  = (__hip_bfloat16*)(ws + 14155776);   // 32768x768
    char* R2 = ws + 64487424;
    __hip_bfloat16* hid = (__hip_bfloat16*)(R2);

    // ---- runtime-tiered attention chunking by workspace size ----
    // per-window q/k/v/ao footprint: 12*196*64*2 = 301056 B per buffer
    const size_t PERWIN = 301056;
    int nwin_chunk, nchunks;
    if (ws_size >= 64487424ull + 4ull * 200 * PERWIN) {         // ~292 MB
        nwin_chunk = 200; nchunks = 1;
    } else if (ws_size >= 64487424ull + 4ull * 100 * PERWIN) {  // ~177 MB
        nwin_chunk = 100; nchunks = 2;
    } else {
        nwin_chunk = 25; nchunks = 8;
    }
    size_t bufsz = (size_t)nwin_chunk * PERWIN;
    __hip_bfloat16* qc = (__hip_bfloat16*)(R2);
    __hip_bfloat16* kc = (__hip_bfloat16*)(R2 + bufsz);
    __hip_bfloat16* vc = (__hip_bfloat16*)(R2 + 2 * bufsz);
    __hip_bfloat16* ao = (__hip_bfloat16*)(R2 + 3 * bufsz);

    // MLP chunking: 2 chunks of 16384 (hid slice 100 MB L3-resident,
    // full-round grids); fallback 4 x 8192
    int mlpch, nmlp;
    if (ws_size >= 64487424ull + (size_t)16384 * 3072 * 2) {
        mlpch = 16384; nmlp = 2;
    } else {
        mlpch = 8192; nmlp = 4;
    }

    cvt_t_k<<<dim3(72, 24), 256, 0, stream>>>(qkv_w,  wqkv,  768, 2304);
    cvt_t_k<<<dim3(24, 24), 256, 0, stream>>>(proj_w, wproj, 768, 768);
    cvt_t_k<<<dim3(96, 24), 256, 0, stream>>>(mlp_w1, wm1,   768, 3072);
    cvt_t_k<<<dim3(24, 96), 256, 0, stream>>>(mlp_w2, wm2,  3072, 768);

    ln_k<<<dim3(8192), 256, 0, stream>>>(x, ln1_g, ln1_b, ybuf);

    for (int c = 0; c < nchunks; ++c) {
        int M = nwin_chunk * TOK;
        int wb = c * nwin_chunk;
        gemm_k<0, 1, 128, 128, 1, 1, 3><<<dim3(18, (M + 127) / 128), 256, 0, stream>>>(
            ybuf, wqkv, qkv_b, M, 2304, 768,
            qc, kc, vc, nullptr, nullptr, nullptr, wb, 0);
        attn_k<<<dim3(nwin_chunk * NHEADS), 256, 0, stream>>>(
            qc, kc, vc, rph, rpw, ao);
        gemm_k<1, 0, 128, 128, 1, 0, 3><<<dim3(6, (M + 127) / 128), 256, 0, stream>>>(
            ao, wproj, proj_b, M, 768, 768,
            nullptr, nullptr, nullptr, out, x, nullptr, wb, 0);
    }

    ln_k<<<dim3(8192), 256, 0, stream>>>(out, ln2_g, ln2_b, ybuf);

    for (int mc = 0; mc < nmlp; ++mc) {
        gemm_k<2, 0, 128, 128, 1, 0, 3><<<dim3(24, mlpch / 128), 256, 0, stream>>>(
            ybuf + (size_t)mc * mlpch * HS, wm1, mlp_b1, mlpch, 3072, 768,
            nullptr, nullptr, nullptr, nullptr, nullptr, hid, 0, 0);
        gemm_k<3, 0, 128, 64, 1, 0, 3><<<dim3(12, mlpch / 128), 256, 0, stream>>>(
            hid, wm2, mlp_b2, mlpch, 768, 3072,
            nullptr, nullptr, nullptr, out, nullptr, nullptr, 0, mc * mlpch);
    }
}

// Round 22
// 1304.705 us; speedup vs baseline: 1.1621x; 1.0172x over previous
//
#include <hip/hip_runtime.h>
#include <hip/hip_bf16.h>
#include <math.h>

// SAM vision layer: LN1 -> windowed attention (decomposed rel-pos bias) -> proj
// + residual -> LN2 -> MLP(GELU exact) -> residual.
// B=8, H=W=64, HS=768, NH=12, HD=64, WS=14 -> 200 windows x 196 tokens.

#define HS 768
#define NHEADS 12
#define HD 64
#define WSZ 14
#define TOK 196
#define HWDIM 64
#define NSIDE 5
#define WIN_PER_B 25

typedef __attribute__((ext_vector_type(8))) short short8;
typedef __attribute__((ext_vector_type(4))) float floatx4;
typedef __attribute__((ext_vector_type(4))) unsigned short ushort4v;

__device__ __forceinline__ float bf2f(unsigned short u) {
    union { unsigned int i; float f; } w; w.i = ((unsigned int)u) << 16; return w.f;
}
__device__ __forceinline__ unsigned short f2bu(float f) {
    __hip_bfloat16 h = __float2bfloat16(f);
    return *(unsigned short*)&h;
}

// async global->LDS, 16B per lane. LDS dest must be wave-uniform base;
// HW writes lane l at base + l*16. Global src is per-lane.
__device__ __forceinline__ void gload16(const void* g, void* l) {
    __builtin_amdgcn_global_load_lds(
        (const __attribute__((address_space(1))) void*)g,
        (__attribute__((address_space(3))) void*)l, 16, 0, 0);
}

// window gather: map output row m (chunk-local) -> source spatial row, or -1
__device__ __forceinline__ int gather_src(int m, int M, int win_base) {
    if (m >= M) return -1;
    int lwin = m / TOK, tok = m - lwin * TOK;
    int win = win_base + lwin;
    int bb = win / WIN_PER_B, r = win - bb * WIN_PER_B;
    int wi = r / NSIDE, wj = r - wi * NSIDE;
    int ti = tok / WSZ, tj = tok - ti * WSZ;
    int h = wi * WSZ + ti, w = wj * WSZ + tj;
    if (h < HWDIM && w < HWDIM) return (bb * HWDIM + h) * HWDIM + w;
    return -1;
}

// ---- fp32 -> bf16 transposed convert via LDS tile: src[K][N] -> dst[N][K].
__global__ __launch_bounds__(256)
void cvt_t_k(const float* __restrict__ src, __hip_bfloat16* __restrict__ dst,
             int K, int N) {
    __shared__ float t[32][33];
    int n0 = blockIdx.x * 32, k0 = blockIdx.y * 32;
    int tc = threadIdx.x & 31, tr8 = threadIdx.x >> 5;   // tr8: 0..7
    #pragma unroll
    for (int i = 0; i < 4; ++i) {
        int r = tr8 + i * 8;
        t[r][tc] = src[(size_t)(k0 + r) * N + n0 + tc];
    }
    __syncthreads();
    #pragma unroll
    for (int i = 0; i < 4; ++i) {
        int r = tr8 + i * 8;
        dst[(size_t)(n0 + r) * K + k0 + tc] = __float2bfloat16(t[tc][r]);
    }
}

// ---- LayerNorm over HS=768: one WAVE per row, float4 loads, shuffle-only
// reduce (no LDS, no barrier). 256 threads = 4 rows/block; grid = rows/4.
__global__ __launch_bounds__(256)
void ln_k(const float* __restrict__ x, const float* __restrict__ g,
          const float* __restrict__ b, __hip_bfloat16* __restrict__ y) {
    int wave = threadIdx.x >> 6, lane = threadIdx.x & 63;
    int row = blockIdx.x * 4 + wave;
    const float4* xr = (const float4*)(x + (size_t)row * HS);
    float4 a0 = xr[lane], a1 = xr[lane + 64], a2 = xr[lane + 128];
    float s = a0.x + a0.y + a0.z + a0.w + a1.x + a1.y + a1.z + a1.w
            + a2.x + a2.y + a2.z + a2.w;
    float q = a0.x*a0.x + a0.y*a0.y + a0.z*a0.z + a0.w*a0.w
            + a1.x*a1.x + a1.y*a1.y + a1.z*a1.z + a1.w*a1.w
            + a2.x*a2.x + a2.y*a2.y + a2.z*a2.z + a2.w*a2.w;
    #pragma unroll
    for (int off = 32; off > 0; off >>= 1) {
        s += __shfl_down(s, off, 64);
        q += __shfl_down(q, off, 64);
    }
    s = __shfl(s, 0, 64);
    q = __shfl(q, 0, 64);
    float mu = s * (1.0f / HS);
    float var = q * (1.0f / HS) - mu * mu;
    float rstd = rsqrtf(var + 1e-6f);
    const float4* g4 = (const float4*)g;
    const float4* b4 = (const float4*)b;
    unsigned short* yr = (unsigned short*)y + (size_t)row * HS;
    float4 av[3] = {a0, a1, a2};
    #pragma unroll
    for (int c = 0; c < 3; ++c) {
        float4 gv = g4[lane + 64 * c], bv = b4[lane + 64 * c];
        float4 a = av[c];
        ushort4v o;
        o[0] = f2bu((a.x - mu) * rstd * gv.x + bv.x);
        o[1] = f2bu((a.y - mu) * rstd * gv.y + bv.y);
        o[2] = f2bu((a.z - mu) * rstd * gv.z + bv.z);
        o[3] = f2bu((a.w - mu) * rstd * gv.w + bv.w);
        *(ushort4v*)&yr[(lane + 64 * c) * 4] = o;
    }
}

// ---- bf16 MFMA GEMM, BM x BN tile, BK=32, 4 waves (2x2), wave tile
// (BM/2)x(BN/2). RING-deep LDS ring with counted vmcnt (up to RING-2 tiles
// stay in flight across the barrier). Both-sides granule XOR swizzle (0 bank
// conflicts, r5). Transposed grid (blockIdx.x = col panel) keeps the A
// row-panel L2-hot. XSWZ=1: bijective XCD swizzle (m204) -- each XCD gets a
// CONTIGUOUS run of x-fastest tile ids, so every A row-panel is fetched by
// ONE XCD's L2 (QKV FETCH 267->186 MB, r19; propagated to proj/MLP r22).
// RING=3 -> 48 KB LDS at 128x128 -> 3 blocks/CU: verified +10% (r20/r21).
// EP0/EP2 epilogues stage the C-tile in LDS and write 128B-contiguous
// segments. Gather-invalid A rows clamp to row 0 (uniform vmcnt); garbage
// discarded at C-stage time.
template<int EP, int AGATHER, int BM, int BN, int KSPLIT, int XSWZ = 0, int RING = 3>
__global__ __launch_bounds__(256, 4)
void gemm_k(const __hip_bfloat16* __restrict__ A,
            const __hip_bfloat16* __restrict__ Bt,
            const float* __restrict__ bias,
            int M, int N, int K,
            __hip_bfloat16* __restrict__ oq, __hip_bfloat16* __restrict__ okk,
            __hip_bfloat16* __restrict__ ov,
            float* __restrict__ of, const float* __restrict__ resid,
            __hip_bfloat16* __restrict__ oh,
            int win_base, int m_base)
{
    constexpr int LPW = (BM + BN) / 64;     // DMA issues per wave per K-step
    constexpr int FI = BM / 32;
    constexpr int FJ = BN / 32;
    constexpr int ASZ = BM * 32;            // shorts per A buffer
    constexpr int BSZ = BN * 32;
    __shared__ __align__(16) unsigned short lds[RING * (ASZ + BSZ)];
    unsigned short* Asb = lds;
    unsigned short* Bsb = lds + RING * ASZ;

    int tid = threadIdx.x;
    int wave = tid >> 6, lane = tid & 63;
    int n16 = lane & 15, quad = lane >> 4;
    int wrr = wave >> 1, wcc = wave & 1;

    int bx = blockIdx.x, by = blockIdx.y;
    if constexpr (XSWZ) {
        // bijective XCD swizzle: HW places block lin on XCD lin%8; give that
        // XCD the contiguous run [pos ...] of x-fastest tile ids.
        int gx = gridDim.x, gy = gridDim.y;
        int lin = by * gx + bx;
        int nwg = gx * gy;
        int qq = nwg >> 3, rr8 = nwg & 7;
        int xcd = lin & 7, pos = lin >> 3;
        int swz = (xcd < rr8) ? (xcd * (qq + 1) + pos)
                              : (rr8 * (qq + 1) + (xcd - rr8) * qq + pos);
        bx = swz % gx;
        by = swz / gx;
    }
    int bm = by * BM;                  // transposed grid
    int bn = bx * BN;
    int kz = (KSPLIT > 1) ? blockIdx.z : 0;
    int kseg = K / KSPLIT;

    int srow = tid >> 2;
    int q4 = tid & 3;
    int skoff = (q4 ^ ((srow >> 1) & 3)) << 3;   // swizzled source granule

    const unsigned short* Au = (const unsigned short*)A;
    const unsigned short* Bu = (const unsigned short*)Bt;

    int src0 = 0, src1 = 0;
    if (AGATHER) {
        int s0 = gather_src(bm + srow, M, win_base);
        src0 = s0 >= 0 ? s0 : 0;
        if (BM == 128) {
            int s1 = gather_src(bm + 64 + srow, M, win_base);
            src1 = s1 >= 0 ? s1 : 0;
        }
    } else {
        int m0 = bm + srow;
        src0 = m0 < M ? m0 : 0;
        if (BM == 128) { int m1 = bm + 64 + srow; src1 = m1 < M ? m1 : 0; }
    }

    const unsigned short* ap0 = Au + (size_t)src0 * K + kz * kseg + skoff;
    const unsigned short* ap1 = Au + (size_t)src1 * K + kz * kseg + skoff;
    const unsigned short* bp0 = Bu + (size_t)(bn + srow) * K + kz * kseg + skoff;
    const unsigned short* bp1 = Bu + (size_t)(bn + 64 + srow) * K + kz * kseg + skoff;

    auto stage = [&](int kt, int b) {
        size_t ko = (size_t)kt * 32;
        gload16(ap0 + ko, Asb + b * ASZ + wave * 512);
        if constexpr (BM == 128) gload16(ap1 + ko, Asb + b * ASZ + 2048 + wave * 512);
        gload16(bp0 + ko, Bsb + b * BSZ + wave * 512);
        if constexpr (BN == 128) gload16(bp1 + ko, Bsb + b * BSZ + 2048 + wave * 512);
    };

    floatx4 acc[FI][FJ] = {};
    int xr = (n16 >> 1) & 3;
    int nt = kseg >> 5;

    // prologue: RING-1 tiles in flight
    stage(0, 0);
    if (nt > 1) stage(1, 1);
    if (RING > 3 && nt > 2) stage(2, 2);

    int cur = 0;
    for (int t = 0; t < nt; ++t) {
        int ahead = nt - 1 - t;
        // allowed outstanding = min(RING-2, ahead) * LPW
        if (RING >= 4 && ahead >= 2) {
            if constexpr (LPW == 4)      asm volatile("s_waitcnt vmcnt(8)" ::: "memory");
            else if constexpr (LPW == 3) asm volatile("s_waitcnt vmcnt(6)" ::: "memory");
            else                         asm volatile("s_waitcnt vmcnt(4)" ::: "memory");
        } else if (ahead >= 1) {
            if constexpr (LPW == 4)      asm volatile("s_waitcnt vmcnt(4)" ::: "memory");
            else if constexpr (LPW == 3) asm volatile("s_waitcnt vmcnt(3)" ::: "memory");
            else                         asm volatile("s_waitcnt vmcnt(2)" ::: "memory");
        } else {
            asm volatile("s_waitcnt vmcnt(0)" ::: "memory");
        }
        __builtin_amdgcn_s_barrier();          // tile t visible to all waves
        if (t + RING - 1 < nt) {
            int nb = cur + RING - 1; if (nb >= RING) nb -= RING;
            stage(t + RING - 1, nb);
        }
        short8 af[FI], bf[FJ];
        #pragma unroll
        for (int i = 0; i < FI; ++i) {
            int ra = wrr * (BM / 2) + i * 16 + n16;
            af[i] = *(const short8*)&Asb[cur * ASZ + ra * 32 + ((quad ^ xr) << 3)];
        }
        #pragma unroll
        for (int j = 0; j < FJ; ++j) {
            int rb = wcc * (BN / 2) + j * 16 + n16;
            bf[j] = *(const short8*)&Bsb[cur * BSZ + rb * 32 + ((quad ^ xr) << 3)];
        }
        #pragma unroll
        for (int i = 0; i < FI; ++i)
            #pragma unroll
            for (int j = 0; j < FJ; ++j)
                acc[i][j] = __builtin_amdgcn_mfma_f32_16x16x32_bf16(
                    af[i], bf[j], acc[i][j], 0, 0, 0);
        asm volatile("s_waitcnt lgkmcnt(0)" ::: "memory");  // reads retired
        cur += 1; if (cur >= RING) cur -= RING;
    }

    int rbase = bm + wrr * (BM / 2) + quad * 4;
    int cbase = bn + wcc * (BN / 2) + n16;

    if constexpr (EP == 0 || EP == 2) {
        // ---- C-tile through LDS: coalesced 128B row-half stores ----
        constexpr int CLD = BN + 8;            // padded bf16 row stride
        __syncthreads();                       // staging ring no longer needed
        unsigned short* Cs = lds;
        int ruseW[FI * 4];
        if (EP == 0) {
            #pragma unroll
            for (int i = 0; i < FI; ++i)
                #pragma unroll
                for (int r = 0; r < 4; ++r)
                    ruseW[i * 4 + r] = gather_src(rbase + i * 16 + r, M, win_base) >= 0;
        }
        #pragma unroll
        for (int j = 0; j < FJ; ++j) {
            int col_l = wcc * (BN / 2) + j * 16 + n16;
            float bcol = bias[bn + col_l];
            #pragma unroll
            for (int i = 0; i < FI; ++i) {
                #pragma unroll
                for (int r = 0; r < 4; ++r) {
                    int row_l = wrr * (BM / 2) + i * 16 + quad * 4 + r;
                    float val = acc[i][j][r] + bcol;
                    float vv;
                    if (EP == 0) {
                        vv = ruseW[i * 4 + r] ? val : bcol;
                    } else {
                        vv = 0.5f * val * (1.0f + erff(val * 0.70710678118654752f));
                    }
                    Cs[row_l * CLD + col_l] = f2bu(vv);
                }
            }
        }
        __syncthreads();
        #pragma unroll
        for (int rep = 0; rep < (BM * (BN / 64)) / 256; ++rep) {
            int idx = rep * 256 + tid;
            int row_l = idx / (BN / 64);
            int half = idx - row_l * (BN / 64);
            int m = bm + row_l;
            if (m < M) {
                unsigned short* srcu = &Cs[row_l * CLD + half * 64];
                unsigned short* dstu;
                if (EP == 0) {
                    int lwin = m / TOK, tok = m - lwin * TOK;
                    int colg = bn + half * 64;
                    int which = colg / HS;
                    int head = (colg - which * HS) >> 6;
                    __hip_bfloat16* dstp = (which == 0) ? oq : ((which == 1) ? okk : ov);
                    dstu = (unsigned short*)dstp +
                           ((size_t)(lwin * NHEADS + head) * TOK + tok) * HD;
                } else {
                    dstu = (unsigned short*)oh + (size_t)m * N + bn + half * 64;
                }
                #pragma unroll
                for (int s = 0; s < 8; ++s)
                    *(uint4*)(dstu + s * 8) = *(const uint4*)(srcu + s * 8);
            }
        }
    } else {
        // ---- direct epilogues (EP1 proj fp32 +resid, EP3 accumulate) ----
        int rowoff[FI * 4];
        int ruse[FI * 4];
        #pragma unroll
        for (int i = 0; i < FI; ++i) {
            #pragma unroll
            for (int r = 0; r < 4; ++r) {
                int ii = i * 4 + r;
                int row = rbase + i * 16 + r;
                if (EP == 1) {
                    int lwin = row / TOK, tok = row - lwin * TOK;
                    int win = win_base + lwin;
                    int bb = win / WIN_PER_B, rr2 = win - bb * WIN_PER_B;
                    int wi = rr2 / NSIDE, wj = rr2 - wi * NSIDE;
                    int ti = tok / WSZ, tj = tok - ti * WSZ;
                    int h = wi * WSZ + ti, w = wj * WSZ + tj;
                    ruse[ii] = (h < HWDIM) && (w < HWDIM);
                    rowoff[ii] = ((bb * HWDIM + h) * HWDIM + w) * HS;
                } else {
                    rowoff[ii] = (m_base + row) * HS;
                    ruse[ii] = 1;
                }
            }
        }
        #pragma unroll
        for (int j = 0; j < FJ; ++j) {
            int col = cbase + j * 16;
            float bcol = bias[col];
            if (EP == 3 && KSPLIT > 1 && kz != 0) bcol = 0.0f;
            #pragma unroll
            for (int i = 0; i < FI; ++i) {
                #pragma unroll
                for (int r = 0; r < 4; ++r) {
                    int ii = i * 4 + r;
                    int row = rbase + i * 16 + r;
                    if (row >= M) continue;
                    float val = acc[i][j][r] + bcol;
                    if (EP == 1) {
                        if (ruse[ii]) {
                            size_t idx = (size_t)rowoff[ii] + col;
                            of[idx] = resid[idx] + val;
                        }
                    } else {
                        size_t idx = (size_t)rowoff[ii] + col;
                        if (KSPLIT > 1) {
                            unsafeAtomicAdd(&of[idx], val);
                        } else {
                            of[idx] += val;
                        }
                    }
                }
            }
        }
    }
}

// ---- MFMA attention. One block per (local window, head); 4 waves.
// rel-pos bias folded INTO the QK^T MFMA via extended K (one-hot cols):
// S[q][k] = (0.125 q)·k + qe·ke where ke = [one-hot(ki), one-hot(kj), 0..]
// (32 extra dims staged once in KE[208][40]) and qe[64+i] = rel[q][ti+13-i],
// qe[78+j] = relw[q][tj+13-j] (8 scalar LDS reads/lane/q-tile instead of the
// old 104-read bias gather). Scale bookkeeping: q-frags x0.125 (exact pow2),
// rel tables x8 at btab build -> rel stays unscaled, QK gets 1/sqrt(d).
// Ks stride 72, Vt stride 232, KE stride 40 (all 2-way/free). LDS 81472 B
// -> 2 blocks/CU. Ks reads for pad rows 196..207 overflow into Vt: finite
// bf16 garbage; KE pad rows staged zero; masked in S (n16>=4 of nt=12).
__global__ __launch_bounds__(256)
void attn_k(const __hip_bfloat16* __restrict__ qb, const __hip_bfloat16* __restrict__ kb,
            const __hip_bfloat16* __restrict__ vb,
            const float* __restrict__ rph, const float* __restrict__ rpw,
            __hip_bfloat16* __restrict__ ao)
{
    __shared__ __align__(16) unsigned short lds[40736];
    unsigned short* Ks = lds;            // [196][72] bf16
    unsigned short* Vt = lds + 14112;    // [64][232] bf16 (cols 196..231 zero)
    unsigned short* KE = lds + 28960;    // [208][40] bf16 one-hot extension
    unsigned short* scr = lds + 37280;   // 4 x 864

    int bid = blockIdx.x;
    int lwin = bid / NHEADS, head = bid - lwin * NHEADS;
    size_t base = (size_t)(lwin * NHEADS + head) * TOK * HD;
    const unsigned short* q = (const unsigned short*)qb + base;
    const unsigned short* k = (const unsigned short*)kb + base;
    const unsigned short* v = (const unsigned short*)vb + base;

    int tid = threadIdx.x;
    int wave = tid >> 6, lane = tid & 63;
    int n16 = lane & 15, quad = lane >> 4;

    // rel tables x8 (compensates the 0.125-scaled q in the rel MFMA)
    short8 btab[4][2];
    #pragma unroll
    for (int nt = 0; nt < 4; ++nt) {
        int n = nt * 16 + n16;
        #pragma unroll
        for (int kh = 0; kh < 2; ++kh) {
            short8 f = {0, 0, 0, 0, 0, 0, 0, 0};
            if (n < 54) {
                const float* src = (n < 27) ? (rph + (size_t)n * HD)
                                            : (rpw + (size_t)(n - 27) * HD);
                const float4* s4 = (const float4*)(src + kh * 32 + quad * 8);
                float4 a = s4[0], b = s4[1];
                f[0] = (short)f2bu(a.x * 8.0f); f[1] = (short)f2bu(a.y * 8.0f);
                f[2] = (short)f2bu(a.z * 8.0f); f[3] = (short)f2bu(a.w * 8.0f);
                f[4] = (short)f2bu(b.x * 8.0f); f[5] = (short)f2bu(b.y * 8.0f);
                f[6] = (short)f2bu(b.z * 8.0f); f[7] = (short)f2bu(b.w * 8.0f);
            }
            btab[nt][kh] = f;
        }
    }

    // ---- stage K: 196 rows x 64 bf16 (stride 72), coalesced uint4 ----
    for (int idx = tid; idx < 1568; idx += 256) {
        int row = idx >> 3, q8 = (idx & 7) << 3;
        *(uint4*)&Ks[row * 72 + q8] = *(const uint4*)(k + (size_t)row * HD + q8);
    }
    // ---- stage V transposed: coalesced uint4 row loads, scalar LDS writes ----
    for (int s = tid; s < 1568; s += 256) {
        int row = s >> 3, d8 = (s & 7) << 3;
        uint4 vv = *(const uint4*)(v + (size_t)row * HD + d8);
        const unsigned short* p = (const unsigned short*)&vv;
        #pragma unroll
        for (int e = 0; e < 8; ++e)
            Vt[(d8 + e) * 232 + row] = p[e];
    }
    for (int s = tid; s < 64 * 9; s += 256) {    // zero cols 196..231
        int r = s / 9, c = 196 + (s - r * 9) * 4;
        uint2 z = {0u, 0u};
        *(uint2*)&Vt[r * 232 + c] = z;
    }
    // ---- stage KE one-hot: rows 0..195 = [1@ki | 1@14+kj | 0 pad]; 196..207 = 0
    for (int krow = tid; krow < 208; krow += 256) {
        int ki = krow / WSZ, kj = krow - ki * WSZ;
        int valid = krow < TOK;
        #pragma unroll
        for (int c = 0; c < 32; ++c) {
            unsigned short vv = 0;
            if (valid && (c == ki || c == 14 + kj)) vv = 0x3F80;  // bf16 1.0
            KE[krow * 40 + c] = vv;
        }
    }
    __syncthreads();

    unsigned short* myscr = &scr[wave * 864];
    int rl0 = quad * 4;

    for (int qt = wave; qt < 13; qt += 4) {
        int qrow = qt * 16 + n16;
        int qr = qrow < 196 ? qrow : 195;

        // load q frags and scale x0.125 (exact: pow2 exponent shift)
        short8 raw0 = *(const short8*)(q + (size_t)qr * HD + quad * 8);
        short8 raw1 = *(const short8*)(q + (size_t)qr * HD + 32 + quad * 8);
        short8 qf0, qf1;
        #pragma unroll
        for (int e = 0; e < 8; ++e) {
            qf0[e] = (short)f2bu(bf2f((unsigned short)raw0[e]) * 0.125f);
            qf1[e] = (short)f2bu(bf2f((unsigned short)raw1[e]) * 0.125f);
        }

        // rel bias via MFMA: rel[16 rows][54 cols] -> scr (unscaled: q/8 * 8tab)
        #pragma unroll
        for (int nt = 0; nt < 4; ++nt) {
            floatx4 cr = {0.f, 0.f, 0.f, 0.f};
            cr = __builtin_amdgcn_mfma_f32_16x16x32_bf16(qf0, btab[nt][0], cr, 0, 0, 0);
            cr = __builtin_amdgcn_mfma_f32_16x16x32_bf16(qf1, btab[nt][1], cr, 0, 0, 0);
            int c = nt * 16 + n16;
            if (c < 54) {
                #pragma unroll
                for (int r = 0; r < 4; ++r)
                    myscr[(rl0 + r) * 54 + c] = f2bu(cr[r]);
            }
        }

        // build extended-q fragment: qe[64+d] picked from this lane's rel row
        int ti_l = qr / WSZ, tj_l = qr - ti_l * WSZ;
        short8 qf2;
        #pragma unroll
        for (int e = 0; e < 8; ++e) {
            int d = quad * 8 + e;
            int idx_i = n16 * 54 + ti_l + 13 - d;
            int idx_j = n16 * 54 + 40 + tj_l - (d - 14);
            int idx = (d < 14) ? idx_i : idx_j;
            unsigned short vv = (d < 28) ? myscr[idx] : (unsigned short)0;
            qf2[e] = (short)vv;
        }

        // S = 0.125*QK^T + bias (3 k-steps: K 0..63 + one-hot 64..95)
        floatx4 S[13];
        __builtin_amdgcn_s_setprio(1);
        #pragma unroll
        for (int nt = 0; nt < 13; ++nt) {
            int kr = nt * 16 + n16;
            short8 kf0 = *(const short8*)&Ks[kr * 72 + quad * 8];
            short8 kf1 = *(const short8*)&Ks[kr * 72 + 32 + quad * 8];
            short8 kf2 = *(const short8*)&KE[kr * 40 + quad * 8];
            floatx4 a = {0.f, 0.f, 0.f, 0.f};
            a = __builtin_amdgcn_mfma_f32_16x16x32_bf16(qf0, kf0, a, 0, 0, 0);
            a = __builtin_amdgcn_mfma_f32_16x16x32_bf16(qf1, kf1, a, 0, 0, 0);
            a = __builtin_amdgcn_mfma_f32_16x16x32_bf16(qf2, kf2, a, 0, 0, 0);
            S[nt] = a;
        }
        __builtin_amdgcn_s_setprio(0);

        if (n16 >= 4) {
            #pragma unroll
            for (int r = 0; r < 4; ++r) S[12][r] = -1e30f;
        }

        float mxr[4] = {-3e30f, -3e30f, -3e30f, -3e30f};
        #pragma unroll
        for (int nt = 0; nt < 13; ++nt)
            #pragma unroll
            for (int r = 0; r < 4; ++r) mxr[r] = fmaxf(mxr[r], S[nt][r]);
        #pragma unroll
        for (int m = 1; m <= 8; m <<= 1)
            #pragma unroll
            for (int r = 0; r < 4; ++r) mxr[r] = fmaxf(mxr[r], __shfl_xor(mxr[r], m, 64));
        float sum[4] = {0.f, 0.f, 0.f, 0.f};
        #pragma unroll
        for (int nt = 0; nt < 13; ++nt)
            #pragma unroll
            for (int r = 0; r < 4; ++r) {
                float e = __expf(S[nt][r] - mxr[r]);
                S[nt][r] = e;
                sum[r] += e;
            }
        #pragma unroll
        for (int m = 1; m <= 8; m <<= 1)
            #pragma unroll
            for (int r = 0; r < 4; ++r) sum[r] += __shfl_xor(sum[r], m, 64);
        float inv[4];
        #pragma unroll
        for (int r = 0; r < 4; ++r) inv[r] = 1.0f / sum[r];

        floatx4 O[4] = {{0.f,0.f,0.f,0.f},{0.f,0.f,0.f,0.f},{0.f,0.f,0.f,0.f},{0.f,0.f,0.f,0.f}};
        __builtin_amdgcn_s_setprio(1);
        #pragma unroll
        for (int ks = 0; ks < 7; ++ks) {
            #pragma unroll
            for (int r = 0; r < 4; ++r) {
                myscr[(rl0 + r) * 40 + n16] = f2bu(S[2 * ks][r] * inv[r]);
                myscr[(rl0 + r) * 40 + 16 + n16] =
                    (2 * ks + 1 < 13) ? f2bu(S[2 * ks + 1][r] * inv[r]) : (unsigned short)0;
            }
            short8 pf = *(const short8*)&myscr[n16 * 40 + quad * 8];
            #pragma unroll
            for (int nt4 = 0; nt4 < 4; ++nt4) {
                short8 vf = *(const short8*)&Vt[(nt4 * 16 + n16) * 232 + ks * 32 + quad * 8];
                O[nt4] = __builtin_amdgcn_mfma_f32_16x16x32_bf16(pf, vf, O[nt4], 0, 0, 0);
            }
        }
        __builtin_amdgcn_s_setprio(0);

        #pragma unroll
        for (int nt4 = 0; nt4 < 4; ++nt4) {
            int d = nt4 * 16 + n16;
            #pragma unroll
            for (int r = 0; r < 4; ++r) {
                int row = qt * 16 + rl0 + r;
                if (row < 196) {
                    ao[((size_t)(lwin * TOK + row)) * HS + head * HD + d] =
                        __float2bfloat16(O[nt4][r]);
                }
            }
        }
    }
}

extern "C" void kernel_launch(void* const* d_in, const int* in_sizes, int n_in,
                              void* d_out, int out_size, void* d_ws, size_t ws_size,
                              hipStream_t stream)
{
    const float* x      = (const float*)d_in[0];
    const float* ln1_g  = (const float*)d_in[1];
    const float* ln1_b  = (const float*)d_in[2];
    const float* qkv_w  = (const float*)d_in[3];
    const float* qkv_b  = (const float*)d_in[4];
    const float* proj_w = (const float*)d_in[5];
    const float* proj_b = (const float*)d_in[6];
    const float* rph    = (const float*)d_in[7];
    const float* rpw    = (const float*)d_in[8];
    const float* ln2_g  = (const float*)d_in[9];
    const float* ln2_b  = (const float*)d_in[10];
    const float* mlp_w1 = (const float*)d_in[11];
    const float* mlp_b1 = (const float*)d_in[12];
    const float* mlp_w2 = (const float*)d_in[13];
    const float* mlp_b2 = (const float*)d_in[14];
    float* out = (float*)d_out;

    char* ws = (char*)d_ws;
    __hip_bfloat16* wqkv  = (__hip_bfloat16*)(ws + 0);          // [2304][768]
    __hip_bfloat16* wproj = (__hip_bfloat16*)(ws + 3538944);    // [768][768]
    __hip_bfloat16* wm1   = (__hip_bfloat16*)(ws + 4718592);    // [3072][768]
    __hip_bfloat16* wm2   = (__hip_bfloat16*)(ws + 9437184);    // [768][3072]
    __hip_bfloat16* ybuf  = (__hip_bfloat16*)(ws + 14155776);   // 32768x768
    char* R2 = ws + 64487424;
    __hip_bfloat16* hid = (__hip_bfloat16*)(R2);

    // ---- runtime-tiered attention chunking by workspace size ----
    // per-window q/k/v/ao footprint: 12*196*64*2 = 301056 B per buffer
    const size_t PERWIN = 301056;
    int nwin_chunk, nchunks;
    if (ws_size >= 64487424ull + 4ull * 200 * PERWIN) {         // ~292 MB
        nwin_chunk = 200; nchunks = 1;
    } else if (ws_size >= 64487424ull + 4ull * 100 * PERWIN) {  // ~177 MB
        nwin_chunk = 100; nchunks = 2;
    } else {
        nwin_chunk = 25; nchunks = 8;
    }
    size_t bufsz = (size_t)nwin_chunk * PERWIN;
    __hip_bfloat16* qc = (__hip_bfloat16*)(R2);
    __hip_bfloat16* kc = (__hip_bfloat16*)(R2 + bufsz);
    __hip_bfloat16* vc = (__hip_bfloat16*)(R2 + 2 * bufsz);
    __hip_bfloat16* ao = (__hip_bfloat16*)(R2 + 3 * bufsz);

    // MLP chunking: 2 chunks of 16384 (hid slice 100 MB L3-resident,
    // full-round grids); fallback 4 x 8192
    int mlpch, nmlp;
    if (ws_size >= 64487424ull + (size_t)16384 * 3072 * 2) {
        mlpch = 16384; nmlp = 2;
    } else {
        mlpch = 8192; nmlp = 4;
    }

    cvt_t_k<<<dim3(72, 24), 256, 0, stream>>>(qkv_w,  wqkv,  768, 2304);
    cvt_t_k<<<dim3(24, 24), 256, 0, stream>>>(proj_w, wproj, 768, 768);
    cvt_t_k<<<dim3(96, 24), 256, 0, stream>>>(mlp_w1, wm1,   768, 3072);
    cvt_t_k<<<dim3(24, 96), 256, 0, stream>>>(mlp_w2, wm2,  3072, 768);

    ln_k<<<dim3(8192), 256, 0, stream>>>(x, ln1_g, ln1_b, ybuf);

    for (int c = 0; c < nchunks; ++c) {
        int M = nwin_chunk * TOK;
        int wb = c * nwin_chunk;
        gemm_k<0, 1, 128, 128, 1, 1, 3><<<dim3(18, (M + 127) / 128), 256, 0, stream>>>(
            ybuf, wqkv, qkv_b, M, 2304, 768,
            qc, kc, vc, nullptr, nullptr, nullptr, wb, 0);
        attn_k<<<dim3(nwin_chunk * NHEADS), 256, 0, stream>>>(
            qc, kc, vc, rph, rpw, ao);
        gemm_k<1, 0, 128, 128, 1, 1, 3><<<dim3(6, (M + 127) / 128), 256, 0, stream>>>(
            ao, wproj, proj_b, M, 768, 768,
            nullptr, nullptr, nullptr, out, x, nullptr, wb, 0);
    }

    ln_k<<<dim3(8192), 256, 0, stream>>>(out, ln2_g, ln2_b, ybuf);

    for (int mc = 0; mc < nmlp; ++mc) {
        gemm_k<2, 0, 128, 128, 1, 1, 3><<<dim3(24, mlpch / 128), 256, 0, stream>>>(
            ybuf + (size_t)mc * mlpch * HS, wm1, mlp_b1, mlpch, 3072, 768,
            nullptr, nullptr, nullptr, nullptr, nullptr, hid, 0, 0);
        gemm_k<3, 0, 128, 64, 1, 1, 3><<<dim3(12, mlpch / 128), 256, 0, stream>>>(
            hid, wm2, mlp_b2, mlpch, 768, 3072,
            nullptr, nullptr, nullptr, out, nullptr, nullptr, 0, mc * mlpch);
    }
}